// Round 10
// baseline (1319.073 us; speedup 1.0000x reference)
//
#include <hip/hip_runtime.h>

#define F 128
#define SPAD 136      // LDS stride (ushorts) for gather S tile
#define NR 16         // rows per tile (16x16 MFMA path)

typedef __attribute__((ext_vector_type(8))) short short8;
typedef __attribute__((ext_vector_type(4))) float f32x4;
typedef unsigned long long ull;

__device__ __forceinline__ float elu_f(float x) {
    return x > 0.f ? x : __expf(x) - 1.f;
}
__device__ __forceinline__ ushort f2bf(float x) {   // fp32 -> bf16 RNE
    unsigned u = __float_as_uint(x);
    u = (u + 0x7FFFu + ((u >> 16) & 1u)) >> 16;
    return (ushort)u;
}
__device__ __forceinline__ float bf2f(ushort u) {
    return __uint_as_float((unsigned)u << 16);
}
__device__ __forceinline__ void bfma8(float* a, float v, short8 u) {
#pragma unroll
    for (int i = 0; i < 8; ++i) a[i] += v * bf2f((ushort)u[i]);
}

// ---------------- fused setup + conv1 ----------------
// blocks 0..87: weight pack (16x16 frag layout); 88..272: rowptr; 273: denom+ACC+CNT zero;
// 274..8465: conv1
struct SetupArgs {
    const float* ws0; const float* ws1; const float* ws2; const float* ws3;
    ushort* wd0; ushort* wd1; ushort* wd2; ushort* wd3;
    const int* rows0; const int* rows1; const int* rows2; const int* rows3; const int* rows4;
    int* rp0; int* rp1; int* rp2; int* rp3; int* rp4;
    const float* mask; float* den; float* acc;   // acc: 14*8*128 floats
    int* cnt;                                    // 7*16 ints, zeroed each run
    const float* in; const float* Wg; const float* bg; const float* Wl; const float* bl;
    ushort* og; ushort* eg; ushort* ol; ushort* el;   // bf16 residual streams
};

__global__ __launch_bounds__(256) void setup_conv1(SetupArgs s) {
    __shared__ ushort tile[16384];
    int b = blockIdx.x, t = threadIdx.x;
    if (b >= 274) {
        int id = (b - 274) * 256 + t;
        int r = id >> 7, c = id & 127;
        float x0 = s.in[r * 3 + 0], x1 = s.in[r * 3 + 1], x2 = s.in[r * 3 + 2];
        float g = x0 * s.Wg[c] + x1 * s.Wg[F + c] + x2 * s.Wg[2 * F + c] + s.bg[c];
        float lo = x0 * s.Wl[c] + x1 * s.Wl[F + c] + x2 * s.Wl[2 * F + c] + s.bl[c];
        s.og[id] = f2bf(g);  s.eg[id] = f2bf(elu_f(g));
        s.ol[id] = f2bf(lo); s.el[id] = f2bf(elu_f(lo));
    } else if (b < 88) {
        const float* src; ushort* dst; int lb;
        if (b < 12)      { src = s.ws0; dst = s.wd0; lb = b; }
        else if (b < 16) { src = s.ws1; dst = s.wd1; lb = b - 12; }
        else if (b < 28) { src = s.ws2; dst = s.wd2; lb = b - 16; }
        else             { src = s.ws3; dst = s.wd3; lb = b - 28; }
        src += (size_t)lb * 16384; dst += (size_t)lb * 16384;
        for (int idx = t; idx < 16384; idx += 256) {
            int k = idx >> 7, nn = idx & 127;
            // 16x16x32 B-frag: lane = lq*16 + col, elem j; k = kt*32 + lq*8 + j
            int kt = k >> 5, lq = (k >> 3) & 3, j = k & 7;
            int wv = nn >> 5, ct = (nn >> 4) & 1, cc = nn & 15;
            tile[((((kt * 4 + wv) * 2 + ct) * 64 + lq * 16 + cc)) * 8 + j] = f2bf(src[idx]);
        }
        __syncthreads();
        ull* td = (ull*)dst; const ull* ts = (const ull*)tile;
        for (int i = t; i < 4096; i += 256) td[i] = ts[i];
    } else if (b < 273) {
        int tid = (b - 88) * 256 + t;
        const int ns[5] = {2048, 4096, 8192, 16384, 16384};
        const int es[5] = {16384, 32768, 65536, 131072, 131072};
        const int* rowsA[5] = {s.rows0, s.rows1, s.rows2, s.rows3, s.rows4};
        int* rpA[5] = {s.rp0, s.rp1, s.rp2, s.rp3, s.rp4};
        int base = 0;
        for (int lv = 0; lv < 5; ++lv) {
            int cnt = ns[lv] + 1;
            if (tid < base + cnt) {
                int r = tid - base;
                const int* rows = rowsA[lv]; int e = es[lv];
                int lo = 0, hi = e;
                while (lo < hi) { int mid = (lo + hi) >> 1; if (rows[mid] < r) lo = mid + 1; else hi = mid; }
                rpA[lv][r] = lo;
                return;
            }
            base += cnt;
        }
    } else {
        __shared__ float red[256];
        float ssum = 0.f;
        for (int i = t; i < 16384; i += 256) ssum += s.mask[i];
        red[t] = ssum; __syncthreads();
        for (int st = 128; st > 0; st >>= 1) { if (t < st) red[t] += red[t + st]; __syncthreads(); }
        if (t == 0) s.den[0] = red[0];
        for (int i = t; i < 14336; i += 256) s.acc[i] = 0.f;
        for (int i = t; i < 112; i += 256) s.cnt[i] = 0;
    }
}

// ---------------- unified layer ----------------
struct LArgs {
    const ushort* EA; const ushort* RES; ushort* OUT; ushort* EAOUT;
    const int* rowptr; const int* cols; const float* vals;
    const ushort* Wp; const float* bias;
    const float* accin; const float* den;    // avg mode: 8-replica ACC of prev slot
    const float* mask; float* accout;        // 8-replica out
    ushort* EO; ushort* EE; const ushort* SKIP;
    int epi;  // 0 none, 1 maxpool2, 2 repeat2+skip
    int fin;  // final-head epilogue
    const float* Finp; const ushort* FEB0;
    const float* FgW2; const float* Fgb2; const float* FlW2; const float* Flb2;
    float* Fout;
};

__device__ __forceinline__ void layer_body(const LArgs& a, int blk, ushort* SS, float* FS) {
    const int t = threadIdx.x;
    const int rbase = blk * NR;
    const int w = t >> 6, l = t & 63;
    const int cl = l & 15, lq = l >> 4;       // col-in-tile / K-octet selector
    const bool lap = (a.rowptr != nullptr);
    const bool avg = (a.accin != nullptr);

    if (lap) {
        // 16 lanes per row, 16 concurrent rows/block; lane-parallel cols/vals
        // (one coalesced load covers 16 edges) + full-window issue (1 load/edge/lane).
        const int grp = t >> 4, l16 = t & 15;
        const int lbase = l & ~15;            // group base lane within wave
        const short8* EA8 = (const short8*)a.EA;
        const int row = rbase + grp;
        const int e0 = a.rowptr[row], e1 = a.rowptr[row + 1];
        float acc0[8];
#pragma unroll
        for (int i = 0; i < 8; ++i) acc0[i] = 0.f;
        int myc = 0; float myv = 0.f;
        if (e0 + l16 < e1) { myc = a.cols[e0 + l16]; myv = a.vals[e0 + l16]; }
#pragma unroll 1
        for (int base = e0; base < e1; base += 16) {
            int nc = 0; float nv = 0.f;
            {
                int en = base + 16 + l16;
                if (en < e1) { nc = a.cols[en]; nv = a.vals[en]; }
            }
#pragma unroll
            for (int half = 0; half < 2; ++half) {
                int hb = base + half * 8;
                if (hb < e1) {
                    int cnt = e1 - hb; if (cnt > 8) cnt = 8;
                    int cc[8];
#pragma unroll
                    for (int k = 0; k < 8; ++k) cc[k] = __shfl(myc, lbase + half * 8 + k, 64);
                    short8 ua[8];
#pragma unroll
                    for (int k = 0; k < 8; ++k)
                        if (k < cnt) ua[k] = EA8[(size_t)cc[k] * 16 + l16];
#pragma unroll
                    for (int k = 0; k < 8; ++k)
                        if (k < cnt) {
                            float v = __shfl(myv, lbase + half * 8 + k, 64);
                            bfma8(acc0, v, ua[k]);
                        }
                }
            }
            myc = nc; myv = nv;
        }
        short8 s0;
#pragma unroll
        for (int i = 0; i < 8; ++i) s0[i] = (short)f2bf(acc0[i]);
        *(short8*)(&SS[grp * SPAD + l16 * 8]) = s0;
        __syncthreads();
    } else if (avg) {
        // avg vector (8-replica sum / denom) as a broadcast bf16 A-row in LDS
        if (t < 128) {
            float s = 0.f;
#pragma unroll
            for (int r = 0; r < 8; ++r) s += a.accin[r * 128 + t];
            SS[t] = f2bf(s / a.den[0]);
        }
        __syncthreads();
    }

    // dense-half A-fragments from EA global: row = rbase+cl, k = kt*32 + lq*8 + j
    short8 afrag[4];
    {
        const ushort* ear = a.EA + (size_t)(rbase + cl) * F + lq * 8;
#pragma unroll
        for (int kt = 0; kt < 4; ++kt) afrag[kt] = *(const short8*)(ear + kt * 32);
    }

    f32x4 accA, accB;   // ct = 0, 1 (named: avoid runtime-indexed regs)
#pragma unroll
    for (int i = 0; i < 4; ++i) { accA[i] = 0.f; accB[i] = 0.f; }
#pragma unroll
    for (int kt = 0; kt < 4; ++kt) {
        short8 b0 = *(const short8*)(a.Wp + (size_t)((((kt * 4 + w) * 2 + 0) * 64 + l) * 8));
        short8 b1 = *(const short8*)(a.Wp + (size_t)((((kt * 4 + w) * 2 + 1) * 64 + l) * 8));
        accA = __builtin_amdgcn_mfma_f32_16x16x32_bf16(afrag[kt], b0, accA, 0, 0, 0);
        accB = __builtin_amdgcn_mfma_f32_16x16x32_bf16(afrag[kt], b1, accB, 0, 0, 0);
    }
    if (lap || avg) {
        const ushort* esr = lap ? &SS[cl * SPAD + lq * 8] : &SS[lq * 8];
#pragma unroll
        for (int kt = 0; kt < 4; ++kt) {
            short8 aa = *(const short8*)(esr + kt * 32);
            short8 b0 = *(const short8*)(a.Wp + 16384 + (size_t)((((kt * 4 + w) * 2 + 0) * 64 + l) * 8));
            short8 b1 = *(const short8*)(a.Wp + 16384 + (size_t)((((kt * 4 + w) * 2 + 1) * 64 + l) * 8));
            accA = __builtin_amdgcn_mfma_f32_16x16x32_bf16(aa, b0, accA, 0, 0, 0);
            accB = __builtin_amdgcn_mfma_f32_16x16x32_bf16(aa, b1, accB, 0, 0, 0);
        }
    }

    // C/D: col = cl (+ct*16), row = lq*4 + reg
    const int col0 = w * 32 + cl, col1 = w * 32 + 16 + cl;
    const float bv0 = a.bias[col0], bv1 = a.bias[col1];
    float outv[8];     // [ct*4 + reg]
#pragma unroll
    for (int reg = 0; reg < 4; ++reg) {
        int r = lq * 4 + reg;
        size_t rg = (size_t)(rbase + r);
        float v0 = accA[reg] + bv0;
        float v1 = accB[reg] + bv1;
        if (a.RES) { v0 += bf2f(a.RES[rg * F + col0]); v1 += bf2f(a.RES[rg * F + col1]); }
        outv[reg] = v0; outv[4 + reg] = v1;
        if (a.OUT) { a.OUT[rg * F + col0] = f2bf(v0); a.OUT[rg * F + col1] = f2bf(v1); }
        if (a.EAOUT) { a.EAOUT[rg * F + col0] = f2bf(elu_f(v0)); a.EAOUT[rg * F + col1] = f2bf(elu_f(v1)); }
    }
    if (a.accout) {
        float p0 = 0.f, p1 = 0.f;
#pragma unroll
        for (int reg = 0; reg < 4; ++reg) {
            float mk = a.mask[rbase + lq * 4 + reg];
            p0 += elu_f(outv[reg]) * mk;
            p1 += elu_f(outv[4 + reg]) * mk;
        }
        p0 += __shfl_xor(p0, 16, 64); p0 += __shfl_xor(p0, 32, 64);
        p1 += __shfl_xor(p1, 16, 64); p1 += __shfl_xor(p1, 32, 64);
        if (l < 16) {
            atomicAdd(a.accout + (blk & 7) * 128 + w * 32 + l, p0);
            atomicAdd(a.accout + (blk & 7) * 128 + w * 32 + 16 + l, p1);
        }
    }
    if (a.epi == 1) {          // fused maxpool2 (pairs lane-local: rows lq*4+{0..3})
        int rb2 = rbase >> 1;
#pragma unroll
        for (int ct = 0; ct < 2; ++ct)
#pragma unroll
            for (int e2 = 0; e2 < 2; ++e2) {
                float pv = fmaxf(outv[ct * 4 + e2 * 2], outv[ct * 4 + e2 * 2 + 1]);
                size_t idx = (size_t)(rb2 + lq * 2 + e2) * F + (ct ? col1 : col0);
                a.EO[idx] = f2bf(pv);
                a.EE[idx] = f2bf(elu_f(pv));
            }
    } else if (a.epi == 2) {   // fused repeat2 + skip add
#pragma unroll
        for (int ct = 0; ct < 2; ++ct)
#pragma unroll
            for (int reg = 0; reg < 4; ++reg) {
                int r = lq * 4 + reg;
                size_t R0 = (size_t)(2 * (rbase + r)) * F + (ct ? col1 : col0);
                float v0 = outv[ct * 4 + reg] + bf2f(a.SKIP[R0]);
                float v1 = outv[ct * 4 + reg] + bf2f(a.SKIP[R0 + F]);
                a.EO[R0] = f2bf(v0);     a.EO[R0 + F] = f2bf(v1);
                a.EE[R0] = f2bf(elu_f(v0)); a.EE[R0 + F] = f2bf(elu_f(v1));
            }
    }
    if (a.fin) {               // fused final head (16 rows/block)
        __syncthreads();
        if (t < 32) FS[t] = 0.f;
        __syncthreads();
#pragma unroll
        for (int ct = 0; ct < 2; ++ct) {
            float lw = a.FlW2[ct ? col1 : col0];
#pragma unroll
            for (int reg = 0; reg < 4; ++reg)
                atomicAdd(&FS[lq * 4 + reg], elu_f(outv[ct * 4 + reg]) * lw);
        }
        for (int idx = t; idx < 16 * 128; idx += 256) {
            int r = idx >> 7, cc = idx & 127;
            atomicAdd(&FS[16 + r], bf2f(a.FEB0[(size_t)(rbase + r) * F + cc]) * a.FgW2[2 * cc]);
        }
        __syncthreads();
        if (t < 16) {
            int rg = rbase + t;
            float base = a.Finp[rg * 3 + 0];
            float sg = FS[16 + t] + a.Fgb2[0] + base;
            float sl = FS[t] + a.Flb2[0] + base;
            float wg = 1.f / (1.f + __expf(-sg));
            a.Fout[rg] = sg;
            a.Fout[16384 + rg] = sl;
            a.Fout[32768 + rg] = wg * sg + (1.f - wg) * sl;
        }
    }
}

__global__ __launch_bounds__(256)
void dual_layer(LArgs A, LArgs B, int nA) {
    __shared__ ushort SS[NR * SPAD];
    __shared__ float FS[64];
    bool isA = (int)blockIdx.x < nA;
    const LArgs& a = isA ? A : B;
    int blk = isA ? blockIdx.x : blockIdx.x - nA;
    layer_body(a, blk, SS, FS);
}

// ---------------- fused avg block (s1+s2 in one dispatch) ----------------
// Cross-block data through the in-kernel barrier is ONLY the 8x128 atomicAdd
// accumulator (device-coherent). s1's per-row output stays in LDS (transposed
// to A-frag layout). All blocks guaranteed co-resident: launch_bounds(256,8)
// => 8 blocks/CU => capacity 2048 >= max grid (1024 local + <=512 global).
struct AvgArgs {
    const ushort* EA;        // LE1 in (elu of prev layer)
    ushort* EAOUT;           // LE1 out (elu of s2 out)
    const ushort* LBin;      // LB residual in
    ushort* LBout;           // LB out
    const ushort* W1; const ushort* W2;
    const float* b1; const float* b2;
    const float* accin;      // ACC[i-1] (prev dispatch, plain read ok)
    float* accmid;           // ACC[i]   (this dispatch, atomics)
    const float* den; const float* mask;
    int* cnt;                // per-layer barrier counter
};

__device__ __forceinline__ void avg_fused_body(const AvgArgs& a, int blk, int nLoc,
                                               ushort* SS, ushort* AV) {
    const int t = threadIdx.x;
    const int rbase = blk * NR;
    const int w = t >> 6, l = t & 63;
    const int cl = l & 15, lq = l >> 4;
    const int col0 = w * 32 + cl, col1 = col0 + 16;

    // ---- phase A (s1): x1 = [elu(x), avg0] @ W1 + b1 ----
    if (t < 128) {
        float s = 0.f;
#pragma unroll
        for (int r = 0; r < 8; ++r) s += a.accin[r * 128 + t];
        AV[t] = f2bf(s / a.den[0]);
    }
    short8 afrag[4];
    {
        const ushort* ear = a.EA + (size_t)(rbase + cl) * F + lq * 8;
#pragma unroll
        for (int kt = 0; kt < 4; ++kt) afrag[kt] = *(const short8*)(ear + kt * 32);
    }
    __syncthreads();

    f32x4 accA, accB;
#pragma unroll
    for (int i = 0; i < 4; ++i) { accA[i] = 0.f; accB[i] = 0.f; }
#pragma unroll
    for (int kt = 0; kt < 4; ++kt) {
        short8 b0 = *(const short8*)(a.W1 + (size_t)((((kt * 4 + w) * 2 + 0) * 64 + l) * 8));
        short8 b1 = *(const short8*)(a.W1 + (size_t)((((kt * 4 + w) * 2 + 1) * 64 + l) * 8));
        accA = __builtin_amdgcn_mfma_f32_16x16x32_bf16(afrag[kt], b0, accA, 0, 0, 0);
        accB = __builtin_amdgcn_mfma_f32_16x16x32_bf16(afrag[kt], b1, accB, 0, 0, 0);
        short8 aa = *(const short8*)(&AV[lq * 8] + kt * 32);
        short8 c0 = *(const short8*)(a.W1 + 16384 + (size_t)((((kt * 4 + w) * 2 + 0) * 64 + l) * 8));
        short8 c1 = *(const short8*)(a.W1 + 16384 + (size_t)((((kt * 4 + w) * 2 + 1) * 64 + l) * 8));
        accA = __builtin_amdgcn_mfma_f32_16x16x32_bf16(aa, c0, accA, 0, 0, 0);
        accB = __builtin_amdgcn_mfma_f32_16x16x32_bf16(aa, c1, accB, 0, 0, 0);
    }
    {
        const float bv0 = a.b1[col0], bv1 = a.b1[col1];
        float p0 = 0.f, p1 = 0.f;
#pragma unroll
        for (int reg = 0; reg < 4; ++reg) {
            int r = lq * 4 + reg;
            float e0 = elu_f(accA[reg] + bv0);
            float e1 = elu_f(accB[reg] + bv1);
            float mk = a.mask[rbase + r];
            p0 += e0 * mk; p1 += e1 * mk;
            SS[r * SPAD + col0] = f2bf(e0);   // transpose tile: [row][col]
            SS[r * SPAD + col1] = f2bf(e1);
        }
        p0 += __shfl_xor(p0, 16, 64); p0 += __shfl_xor(p0, 32, 64);
        p1 += __shfl_xor(p1, 16, 64); p1 += __shfl_xor(p1, 32, 64);
        if (l < 16) {
            atomicAdd(a.accmid + (blk & 7) * 128 + w * 32 + l, p0);
            atomicAdd(a.accmid + (blk & 7) * 128 + w * 32 + 16 + l, p1);
        }
    }

    // ---- barrier: only accmid (atomics) crosses ----
    __syncthreads();
    if (t == 0) {
        __hip_atomic_fetch_add(a.cnt, 1, __ATOMIC_ACQ_REL, __HIP_MEMORY_SCOPE_AGENT);
        while (__hip_atomic_load(a.cnt, __ATOMIC_ACQUIRE, __HIP_MEMORY_SCOPE_AGENT) < nLoc)
            __builtin_amdgcn_s_sleep(2);
    }
    __syncthreads();

    // ---- phase B (s2): x2 = [elu(x1), avg1] @ W2 + b2 + LB ----
    if (t < 128) {
        float s = 0.f;
#pragma unroll
        for (int r = 0; r < 8; ++r)
            s += __hip_atomic_load(a.accmid + r * 128 + t, __ATOMIC_RELAXED,
                                   __HIP_MEMORY_SCOPE_AGENT);
        AV[t] = f2bf(s / a.den[0]);
    }
    short8 af2[4];
    {
        const ushort* esr = &SS[cl * SPAD + lq * 8];
#pragma unroll
        for (int kt = 0; kt < 4; ++kt) af2[kt] = *(const short8*)(esr + kt * 32);
    }
    __syncthreads();

#pragma unroll
    for (int i = 0; i < 4; ++i) { accA[i] = 0.f; accB[i] = 0.f; }
#pragma unroll
    for (int kt = 0; kt < 4; ++kt) {
        short8 b0 = *(const short8*)(a.W2 + (size_t)((((kt * 4 + w) * 2 + 0) * 64 + l) * 8));
        short8 b1 = *(const short8*)(a.W2 + (size_t)((((kt * 4 + w) * 2 + 1) * 64 + l) * 8));
        accA = __builtin_amdgcn_mfma_f32_16x16x32_bf16(af2[kt], b0, accA, 0, 0, 0);
        accB = __builtin_amdgcn_mfma_f32_16x16x32_bf16(af2[kt], b1, accB, 0, 0, 0);
        short8 aa = *(const short8*)(&AV[lq * 8] + kt * 32);
        short8 c0 = *(const short8*)(a.W2 + 16384 + (size_t)((((kt * 4 + w) * 2 + 0) * 64 + l) * 8));
        short8 c1 = *(const short8*)(a.W2 + 16384 + (size_t)((((kt * 4 + w) * 2 + 1) * 64 + l) * 8));
        accA = __builtin_amdgcn_mfma_f32_16x16x32_bf16(aa, c0, accA, 0, 0, 0);
        accB = __builtin_amdgcn_mfma_f32_16x16x32_bf16(aa, c1, accB, 0, 0, 0);
    }
    {
        const float bv0 = a.b2[col0], bv1 = a.b2[col1];
#pragma unroll
        for (int reg = 0; reg < 4; ++reg) {
            int r = lq * 4 + reg;
            size_t rg = (size_t)(rbase + r);
            float v0 = accA[reg] + bv0 + bf2f(a.LBin[rg * F + col0]);
            float v1 = accB[reg] + bv1 + bf2f(a.LBin[rg * F + col1]);
            a.LBout[rg * F + col0] = f2bf(v0);
            a.LBout[rg * F + col1] = f2bf(v1);
            a.EAOUT[rg * F + col0] = f2bf(elu_f(v0));
            a.EAOUT[rg * F + col1] = f2bf(elu_f(v1));
        }
    }
}

__global__ __launch_bounds__(256, 8)
void dual_avg(LArgs G, AvgArgs V, int nA, int nLoc) {
    __shared__ ushort SS[NR * SPAD];
    __shared__ ushort AV[128];
    __shared__ float FS[64];
    if ((int)blockIdx.x < nA) layer_body(G, blockIdx.x, SS, FS);
    else avg_fused_body(V, (int)blockIdx.x - nA, nLoc, SS, AV);
}

extern "C" void kernel_launch(void* const* d_in, const int* in_sizes, int n_in,
                              void* d_out, int out_size, void* d_ws, size_t ws_size,
                              hipStream_t stream) {
    (void)in_sizes; (void)n_in; (void)out_size; (void)ws_size;
    const float* inputs = (const float*)d_in[0];
    const float* mask1  = (const float*)d_in[2];
    const int*   lrows[5] = {(const int*)d_in[3], (const int*)d_in[6], (const int*)d_in[9],
                             (const int*)d_in[12], (const int*)d_in[15]};
    const int*   lcols[5] = {(const int*)d_in[4], (const int*)d_in[7], (const int*)d_in[10],
                             (const int*)d_in[13], (const int*)d_in[16]};
    const float* lvals[5] = {(const float*)d_in[5], (const float*)d_in[8], (const float*)d_in[11],
                             (const float*)d_in[14], (const float*)d_in[17]};
    const float* gW1 = (const float*)d_in[18];
    const float* gb1 = (const float*)d_in[19];
    const float* gdW = (const float*)d_in[20];
    const float* gdb = (const float*)d_in[21];
    const float* glW = (const float*)d_in[22];
    const float* glb = (const float*)d_in[23];
    const float* guW = (const float*)d_in[24];
    const float* gub = (const float*)d_in[25];
    const float* gW2 = (const float*)d_in[26];
    const float* gb2 = (const float*)d_in[27];
    const float* lW1 = (const float*)d_in[28];
    const float* lb1 = (const float*)d_in[29];
    const float* lrW = (const float*)d_in[30];
    const float* lrb = (const float*)d_in[31];
    const float* lW2 = (const float*)d_in[32];
    const float* lb2 = (const float*)d_in[33];
    float* out = (float*)d_out;

    const int N = 16384;
    const int nlev[5] = {2048, 4096, 8192, 16384, 16384};

    char* ws = (char*)d_ws;
    size_t off = 0;
    auto alloc = [&](size_t bytes) -> char* {
        char* p = ws + off;
        off = (off + bytes + 255) & ~(size_t)255;
        return p;
    };
    // bf16 residual / skip / pool streams
    ushort* BUF0 = (ushort*)alloc((size_t)N * F * 2);
    ushort* GU2  = (ushort*)alloc((size_t)N * F * 2);
    ushort* G2   = (ushort*)alloc((size_t)N * F * 2);
    ushort* D8   = (ushort*)alloc((size_t)8192 * F * 2);
    ushort* D4   = (ushort*)alloc((size_t)4096 * F * 2);
    ushort* D2   = (ushort*)alloc((size_t)2048 * F * 2);
    ushort* LB   = (ushort*)alloc((size_t)N * F * 2);
    ushort* EB0 = (ushort*)alloc((size_t)N * F * 2);
    ushort* EG1 = (ushort*)alloc((size_t)N * F * 2);
    ushort* EG2 = (ushort*)alloc((size_t)N * F * 2);
    ushort* ED8 = (ushort*)alloc((size_t)8192 * F * 2);
    ushort* ED4 = (ushort*)alloc((size_t)4096 * F * 2);
    ushort* ED2 = (ushort*)alloc((size_t)2048 * F * 2);
    ushort* LE1 = (ushort*)alloc((size_t)N * F * 2);
    ushort* LE2 = (ushort*)alloc((size_t)N * F * 2);
    int* rp[5];
    for (int i = 0; i < 5; ++i) rp[i] = (int*)alloc((size_t)(nlev[i] + 1) * 4);
    float* ACC = (float*)alloc((size_t)14 * 8 * 128 * 4);   // 8 replicas per slot
    float* DEN = (float*)alloc(4);
    int* CNT = (int*)alloc((size_t)7 * 16 * 4);
    ushort* Pd = (ushort*)alloc((size_t)12 * 16384 * 2);
    ushort* Pl = (ushort*)alloc((size_t)4  * 16384 * 2);
    ushort* Pu = (ushort*)alloc((size_t)12 * 16384 * 2);
    ushort* Pr = (ushort*)alloc((size_t)60 * 16384 * 2);

    SetupArgs sa;
    sa.ws0 = gdW; sa.ws1 = glW; sa.ws2 = guW; sa.ws3 = lrW;
    sa.wd0 = Pd;  sa.wd1 = Pl;  sa.wd2 = Pu;  sa.wd3 = Pr;
    sa.rows0 = lrows[0]; sa.rows1 = lrows[1]; sa.rows2 = lrows[2];
    sa.rows3 = lrows[3]; sa.rows4 = lrows[4];
    sa.rp0 = rp[0]; sa.rp1 = rp[1]; sa.rp2 = rp[2]; sa.rp3 = rp[3]; sa.rp4 = rp[4];
    sa.mask = mask1; sa.den = DEN; sa.acc = ACC; sa.cnt = CNT;
    sa.in = inputs; sa.Wg = gW1; sa.bg = gb1; sa.Wl = lW1; sa.bl = lb1;
    sa.og = BUF0; sa.eg = EB0; sa.ol = LB; sa.el = LE1;
    setup_conv1<<<274 + 8192, 256, 0, stream>>>(sa);

    const size_t PSZ = 2 * 16384;   // packed bf16 stride per sub-layer (2 halves)

    auto mkL = [&](const ushort* ea, const ushort* res, ushort* o, ushort* eao,
                   int lv, const ushort* wp, const float* bias, float* accout,
                   int epi, ushort* eo, ushort* ee, const ushort* skip,
                   const float* accin, int fin) {
        LArgs x;
        x.EA = ea; x.RES = res; x.OUT = o; x.EAOUT = eao;
        x.rowptr = (lv >= 0) ? rp[lv] : nullptr;
        x.cols = (lv >= 0) ? lcols[lv] : nullptr;
        x.vals = (lv >= 0) ? lvals[lv] : nullptr;
        x.Wp = wp; x.bias = bias;
        x.accin = accin; x.den = DEN;
        x.mask = mask1; x.accout = accout;
        x.EO = eo; x.EE = ee; x.SKIP = skip; x.epi = epi;
        x.fin = fin;
        x.Finp = inputs; x.FEB0 = EB0;
        x.FgW2 = gW2; x.Fgb2 = gb2; x.FlW2 = lW2; x.Flb2 = lb2; x.Fout = out;
        return x;
    };

    // ---- global branch slots (pool/upadd fused into sub2 epilogues) ----
    LArgs gs[14]; int gn[14];
    gs[0]  = mkL(EB0, 0, 0, EG1, 3, Pd + 0 * PSZ, gdb + 0,   0, 0, 0, 0, 0, 0, 0);  gn[0]  = 16384;
    gs[1]  = mkL(EG1, BUF0, 0, 0, 3, Pd + 1 * PSZ, gdb + 128, 0, 1, D8, ED8, 0, 0, 0); gn[1] = 16384;
    gs[2]  = mkL(ED8, 0, 0, EG1, 2, Pd + 2 * PSZ, gdb + 256, 0, 0, 0, 0, 0, 0, 0);  gn[2]  = 8192;
    gs[3]  = mkL(EG1, D8, 0, 0, 2, Pd + 3 * PSZ, gdb + 384, 0, 1, D4, ED4, 0, 0, 0); gn[3]  = 8192;
    gs[4]  = mkL(ED4, 0, 0, EG1, 1, Pd + 4 * PSZ, gdb + 512, 0, 0, 0, 0, 0, 0, 0);  gn[4]  = 4096;
    gs[5]  = mkL(EG1, D4, 0, 0, 1, Pd + 5 * PSZ, gdb + 640, 0, 1, D2, ED2, 0, 0, 0); gn[5]  = 4096;
    gs[6]  = mkL(ED2, 0, 0, EG1, 0, Pl + 0 * PSZ, glb + 0,   0, 0, 0, 0, 0, 0, 0);  gn[6]  = 2048;
    gs[7]  = mkL(EG1, D2, 0, 0, 0, Pl + 1 * PSZ, glb + 128, 0, 2, GU2, EG2, D4, 0, 0); gn[7] = 2048;
    gs[8]  = mkL(EG2, 0, 0, EG1, 1, Pu + 0 * PSZ, gub + 0,   0, 0, 0, 0, 0, 0, 0);  gn[8]  = 4096;
    gs[9]  = mkL(EG1, GU2, 0, 0, 1, Pu + 1 * PSZ, gub + 128, 0, 2, G2, EG2, D8, 0, 0); gn[9] = 4096;
    gs[10] = mkL(EG2, 0, 0, EG1, 2, Pu + 2 * PSZ, gub + 256, 0, 0, 0, 0, 0, 0, 0);  gn[10] = 8192;
    gs[11] = mkL(EG1, G2, 0, 0, 2, Pu + 3 * PSZ, gub + 384, 0, 2, GU2, EG2, BUF0, 0, 0); gn[11] = 8192;
    gs[12] = mkL(EG2, 0, 0, EG1, 3, Pu + 4 * PSZ, gub + 512, 0, 0, 0, 0, 0, 0, 0);  gn[12] = 16384;
    gs[13] = mkL(EG1, GU2, 0, EB0, 3, Pu + 5 * PSZ, gub + 640, 0, 0, 0, 0, 0, 0, 0); gn[13] = 16384;

    const int NB_LOC = N / NR;   // 1024 local blocks
    int gi = 0;
    auto launchLap = [&](const LArgs& loc) {
        if (gi < 14) {
            int na = gn[gi] / NR;
            dual_layer<<<na + NB_LOC, 256, 0, stream>>>(gs[gi], loc, na);
            ++gi;
        } else {
            dual_layer<<<NB_LOC, 256, 0, stream>>>(loc, loc, NB_LOC);
        }
    };

    for (int i = 0; i < 15; ++i) {
        const ushort* P1 = Pr + (size_t)(2 * i) * PSZ;
        const ushort* P2 = Pr + (size_t)(2 * i + 1) * PSZ;
        const float* b1 = lrb + (size_t)i * 256;
        const float* b2 = b1 + 128;
        if ((i & 1) == 0) {   // lap block on L (level 4)
            LArgs s1 = mkL(LE1, 0, 0, LE2, 4, P1, b1, 0, 0, 0, 0, 0, 0, 0);
            float* accout = (i <= 12) ? (ACC + (size_t)i * 1024) : nullptr;
            int fin = (i == 14);
            LArgs s2 = mkL(LE2, LB, fin ? nullptr : LB, fin ? nullptr : LE1, 4,
                           P2, b2, accout, 0, 0, 0, 0, 0, fin);
            launchLap(s1);
            launchLap(s2);
        } else {              // avg block: fused s1+s2, atomics-only in-kernel barrier
            AvgArgs v;
            v.EA = LE1; v.EAOUT = LE1;
            v.LBin = LB; v.LBout = LB;
            v.W1 = P1; v.W2 = P2;
            v.b1 = b1; v.b2 = b2;
            v.accin = ACC + (size_t)(i - 1) * 1024;
            v.accmid = ACC + (size_t)i * 1024;
            v.den = DEN; v.mask = mask1;
            v.cnt = CNT + (size_t)(i >> 1) * 16;
            if (gi < 14) {
                int na = gn[gi] / NR;
                dual_avg<<<na + NB_LOC, 256, 0, stream>>>(gs[gi], v, na, NB_LOC);
                ++gi;
            } else {
                dual_avg<<<NB_LOC, 256, 0, stream>>>(gs[0], v, 0, NB_LOC);
            }
        }
    }
}

// Round 11
// 1134.165 us; speedup vs baseline: 1.1630x; 1.1630x over previous
//
#include <hip/hip_runtime.h>

#define F 128
#define SPAD 136      // LDS stride (ushorts) for gather S tile
#define NR 16         // rows per tile (16x16 MFMA path)

typedef __attribute__((ext_vector_type(8))) short short8;
typedef __attribute__((ext_vector_type(4))) float f32x4;
typedef unsigned long long ull;

__device__ __forceinline__ float elu_f(float x) {
    return x > 0.f ? x : __expf(x) - 1.f;
}
__device__ __forceinline__ ushort f2bf(float x) {   // fp32 -> bf16 RNE
    unsigned u = __float_as_uint(x);
    u = (u + 0x7FFFu + ((u >> 16) & 1u)) >> 16;
    return (ushort)u;
}
__device__ __forceinline__ float bf2f(ushort u) {
    return __uint_as_float((unsigned)u << 16);
}
__device__ __forceinline__ void bfma8(float* a, float v, short8 u) {
#pragma unroll
    for (int i = 0; i < 8; ++i) a[i] += v * bf2f((ushort)u[i]);
}

// ---------------- fused setup + conv1 ----------------
// blocks 0..87: weight pack (16x16 frag layout); 88..272: rowptr; 273: denom+ACC+CNT zero;
// 274..8465: conv1
struct SetupArgs {
    const float* ws0; const float* ws1; const float* ws2; const float* ws3;
    ushort* wd0; ushort* wd1; ushort* wd2; ushort* wd3;
    const int* rows0; const int* rows1; const int* rows2; const int* rows3; const int* rows4;
    int* rp0; int* rp1; int* rp2; int* rp3; int* rp4;
    const float* mask; float* den; float* acc;   // acc: 14*8*128 floats
    int* cnt;                                    // 7*16 ints, zeroed each run
    const float* in; const float* Wg; const float* bg; const float* Wl; const float* bl;
    ushort* og; ushort* eg; ushort* ol; ushort* el;   // bf16 residual streams
};

__global__ __launch_bounds__(256) void setup_conv1(SetupArgs s) {
    __shared__ ushort tile[16384];
    int b = blockIdx.x, t = threadIdx.x;
    if (b >= 274) {
        int id = (b - 274) * 256 + t;
        int r = id >> 7, c = id & 127;
        float x0 = s.in[r * 3 + 0], x1 = s.in[r * 3 + 1], x2 = s.in[r * 3 + 2];
        float g = x0 * s.Wg[c] + x1 * s.Wg[F + c] + x2 * s.Wg[2 * F + c] + s.bg[c];
        float lo = x0 * s.Wl[c] + x1 * s.Wl[F + c] + x2 * s.Wl[2 * F + c] + s.bl[c];
        s.og[id] = f2bf(g);  s.eg[id] = f2bf(elu_f(g));
        s.ol[id] = f2bf(lo); s.el[id] = f2bf(elu_f(lo));
    } else if (b < 88) {
        const float* src; ushort* dst; int lb;
        if (b < 12)      { src = s.ws0; dst = s.wd0; lb = b; }
        else if (b < 16) { src = s.ws1; dst = s.wd1; lb = b - 12; }
        else if (b < 28) { src = s.ws2; dst = s.wd2; lb = b - 16; }
        else             { src = s.ws3; dst = s.wd3; lb = b - 28; }
        src += (size_t)lb * 16384; dst += (size_t)lb * 16384;
        for (int idx = t; idx < 16384; idx += 256) {
            int k = idx >> 7, nn = idx & 127;
            // 16x16x32 B-frag: lane = lq*16 + col, elem j; k = kt*32 + lq*8 + j
            int kt = k >> 5, lq = (k >> 3) & 3, j = k & 7;
            int wv = nn >> 5, ct = (nn >> 4) & 1, cc = nn & 15;
            tile[((((kt * 4 + wv) * 2 + ct) * 64 + lq * 16 + cc)) * 8 + j] = f2bf(src[idx]);
        }
        __syncthreads();
        ull* td = (ull*)dst; const ull* ts = (const ull*)tile;
        for (int i = t; i < 4096; i += 256) td[i] = ts[i];
    } else if (b < 273) {
        int tid = (b - 88) * 256 + t;
        const int ns[5] = {2048, 4096, 8192, 16384, 16384};
        const int es[5] = {16384, 32768, 65536, 131072, 131072};
        const int* rowsA[5] = {s.rows0, s.rows1, s.rows2, s.rows3, s.rows4};
        int* rpA[5] = {s.rp0, s.rp1, s.rp2, s.rp3, s.rp4};
        int base = 0;
        for (int lv = 0; lv < 5; ++lv) {
            int cnt = ns[lv] + 1;
            if (tid < base + cnt) {
                int r = tid - base;
                const int* rows = rowsA[lv]; int e = es[lv];
                int lo = 0, hi = e;
                while (lo < hi) { int mid = (lo + hi) >> 1; if (rows[mid] < r) lo = mid + 1; else hi = mid; }
                rpA[lv][r] = lo;
                return;
            }
            base += cnt;
        }
    } else {
        __shared__ float red[256];
        float ssum = 0.f;
        for (int i = t; i < 16384; i += 256) ssum += s.mask[i];
        red[t] = ssum; __syncthreads();
        for (int st = 128; st > 0; st >>= 1) { if (t < st) red[t] += red[t + st]; __syncthreads(); }
        if (t == 0) s.den[0] = red[0];
        for (int i = t; i < 14336; i += 256) s.acc[i] = 0.f;
        for (int i = t; i < 112; i += 256) s.cnt[i] = 0;
    }
}

// ---------------- unified layer ----------------
struct LArgs {
    const ushort* EA; const ushort* RES; ushort* OUT; ushort* EAOUT;
    const int* rowptr; const int* cols; const float* vals;
    const ushort* Wp; const float* bias;
    const float* accin; const float* den;    // avg mode: 8-replica ACC of prev slot
    const float* mask; float* accout;        // 8-replica out
    ushort* EO; ushort* EE; const ushort* SKIP;
    int epi;  // 0 none, 1 maxpool2, 2 repeat2+skip
    int fin;  // final-head epilogue
    const float* Finp; const ushort* FEB0;
    const float* FgW2; const float* Fgb2; const float* FlW2; const float* Flb2;
    float* Fout;
};

__device__ __forceinline__ void layer_body(const LArgs& a, int blk, ushort* SS, float* FS) {
    const int t = threadIdx.x;
    const int rbase = blk * NR;
    const int w = t >> 6, l = t & 63;
    const int cl = l & 15, lq = l >> 4;       // col-in-tile / K-octet selector
    const bool lap = (a.rowptr != nullptr);
    const bool avg = (a.accin != nullptr);

    if (lap) {
        // 16 lanes per row, 16 concurrent rows/block; lane-parallel cols/vals
        // (one coalesced load covers 16 edges) + full-window issue (1 load/edge/lane).
        const int grp = t >> 4, l16 = t & 15;
        const int lbase = l & ~15;            // group base lane within wave
        const short8* EA8 = (const short8*)a.EA;
        const int row = rbase + grp;
        const int e0 = a.rowptr[row], e1 = a.rowptr[row + 1];
        float acc0[8];
#pragma unroll
        for (int i = 0; i < 8; ++i) acc0[i] = 0.f;
        int myc = 0; float myv = 0.f;
        if (e0 + l16 < e1) { myc = a.cols[e0 + l16]; myv = a.vals[e0 + l16]; }
#pragma unroll 1
        for (int base = e0; base < e1; base += 16) {
            int nc = 0; float nv = 0.f;
            {
                int en = base + 16 + l16;
                if (en < e1) { nc = a.cols[en]; nv = a.vals[en]; }
            }
#pragma unroll
            for (int half = 0; half < 2; ++half) {
                int hb = base + half * 8;
                if (hb < e1) {
                    int cnt = e1 - hb; if (cnt > 8) cnt = 8;
                    int cc[8];
#pragma unroll
                    for (int k = 0; k < 8; ++k) cc[k] = __shfl(myc, lbase + half * 8 + k, 64);
                    short8 ua[8];
#pragma unroll
                    for (int k = 0; k < 8; ++k)
                        if (k < cnt) ua[k] = EA8[(size_t)cc[k] * 16 + l16];
#pragma unroll
                    for (int k = 0; k < 8; ++k)
                        if (k < cnt) {
                            float v = __shfl(myv, lbase + half * 8 + k, 64);
                            bfma8(acc0, v, ua[k]);
                        }
                }
            }
            myc = nc; myv = nv;
        }
        short8 s0;
#pragma unroll
        for (int i = 0; i < 8; ++i) s0[i] = (short)f2bf(acc0[i]);
        *(short8*)(&SS[grp * SPAD + l16 * 8]) = s0;
        __syncthreads();
    } else if (avg) {
        // avg vector (8-replica sum / denom) as a broadcast bf16 A-row in LDS
        if (t < 128) {
            float s = 0.f;
#pragma unroll
            for (int r = 0; r < 8; ++r) s += a.accin[r * 128 + t];
            SS[t] = f2bf(s / a.den[0]);
        }
        __syncthreads();
    }

    // dense-half A-fragments from EA global: row = rbase+cl, k = kt*32 + lq*8 + j
    short8 afrag[4];
    {
        const ushort* ear = a.EA + (size_t)(rbase + cl) * F + lq * 8;
#pragma unroll
        for (int kt = 0; kt < 4; ++kt) afrag[kt] = *(const short8*)(ear + kt * 32);
    }

    f32x4 accA, accB;   // ct = 0, 1 (named: avoid runtime-indexed regs)
#pragma unroll
    for (int i = 0; i < 4; ++i) { accA[i] = 0.f; accB[i] = 0.f; }
#pragma unroll
    for (int kt = 0; kt < 4; ++kt) {
        short8 b0 = *(const short8*)(a.Wp + (size_t)((((kt * 4 + w) * 2 + 0) * 64 + l) * 8));
        short8 b1 = *(const short8*)(a.Wp + (size_t)((((kt * 4 + w) * 2 + 1) * 64 + l) * 8));
        accA = __builtin_amdgcn_mfma_f32_16x16x32_bf16(afrag[kt], b0, accA, 0, 0, 0);
        accB = __builtin_amdgcn_mfma_f32_16x16x32_bf16(afrag[kt], b1, accB, 0, 0, 0);
    }
    if (lap || avg) {
        const ushort* esr = lap ? &SS[cl * SPAD + lq * 8] : &SS[lq * 8];
#pragma unroll
        for (int kt = 0; kt < 4; ++kt) {
            short8 aa = *(const short8*)(esr + kt * 32);
            short8 b0 = *(const short8*)(a.Wp + 16384 + (size_t)((((kt * 4 + w) * 2 + 0) * 64 + l) * 8));
            short8 b1 = *(const short8*)(a.Wp + 16384 + (size_t)((((kt * 4 + w) * 2 + 1) * 64 + l) * 8));
            accA = __builtin_amdgcn_mfma_f32_16x16x32_bf16(aa, b0, accA, 0, 0, 0);
            accB = __builtin_amdgcn_mfma_f32_16x16x32_bf16(aa, b1, accB, 0, 0, 0);
        }
    }

    // C/D: col = cl (+ct*16), row = lq*4 + reg
    const int col0 = w * 32 + cl, col1 = w * 32 + 16 + cl;
    const float bv0 = a.bias[col0], bv1 = a.bias[col1];
    float outv[8];     // [ct*4 + reg]
#pragma unroll
    for (int reg = 0; reg < 4; ++reg) {
        int r = lq * 4 + reg;
        size_t rg = (size_t)(rbase + r);
        float v0 = accA[reg] + bv0;
        float v1 = accB[reg] + bv1;
        if (a.RES) { v0 += bf2f(a.RES[rg * F + col0]); v1 += bf2f(a.RES[rg * F + col1]); }
        outv[reg] = v0; outv[4 + reg] = v1;
        if (a.OUT) { a.OUT[rg * F + col0] = f2bf(v0); a.OUT[rg * F + col1] = f2bf(v1); }
        if (a.EAOUT) { a.EAOUT[rg * F + col0] = f2bf(elu_f(v0)); a.EAOUT[rg * F + col1] = f2bf(elu_f(v1)); }
    }
    if (a.accout) {
        float p0 = 0.f, p1 = 0.f;
#pragma unroll
        for (int reg = 0; reg < 4; ++reg) {
            float mk = a.mask[rbase + lq * 4 + reg];
            p0 += elu_f(outv[reg]) * mk;
            p1 += elu_f(outv[4 + reg]) * mk;
        }
        p0 += __shfl_xor(p0, 16, 64); p0 += __shfl_xor(p0, 32, 64);
        p1 += __shfl_xor(p1, 16, 64); p1 += __shfl_xor(p1, 32, 64);
        if (l < 16) {
            atomicAdd(a.accout + (blk & 7) * 128 + w * 32 + l, p0);
            atomicAdd(a.accout + (blk & 7) * 128 + w * 32 + 16 + l, p1);
        }
    }
    if (a.epi == 1) {          // fused maxpool2 (pairs lane-local: rows lq*4+{0..3})
        int rb2 = rbase >> 1;
#pragma unroll
        for (int ct = 0; ct < 2; ++ct)
#pragma unroll
            for (int e2 = 0; e2 < 2; ++e2) {
                float pv = fmaxf(outv[ct * 4 + e2 * 2], outv[ct * 4 + e2 * 2 + 1]);
                size_t idx = (size_t)(rb2 + lq * 2 + e2) * F + (ct ? col1 : col0);
                a.EO[idx] = f2bf(pv);
                a.EE[idx] = f2bf(elu_f(pv));
            }
    } else if (a.epi == 2) {   // fused repeat2 + skip add
#pragma unroll
        for (int ct = 0; ct < 2; ++ct)
#pragma unroll
            for (int reg = 0; reg < 4; ++reg) {
                int r = lq * 4 + reg;
                size_t R0 = (size_t)(2 * (rbase + r)) * F + (ct ? col1 : col0);
                float v0 = outv[ct * 4 + reg] + bf2f(a.SKIP[R0]);
                float v1 = outv[ct * 4 + reg] + bf2f(a.SKIP[R0 + F]);
                a.EO[R0] = f2bf(v0);     a.EO[R0 + F] = f2bf(v1);
                a.EE[R0] = f2bf(elu_f(v0)); a.EE[R0 + F] = f2bf(elu_f(v1));
            }
    }
    if (a.fin) {               // fused final head (16 rows/block)
        __syncthreads();
        if (t < 32) FS[t] = 0.f;
        __syncthreads();
#pragma unroll
        for (int ct = 0; ct < 2; ++ct) {
            float lw = a.FlW2[ct ? col1 : col0];
#pragma unroll
            for (int reg = 0; reg < 4; ++reg)
                atomicAdd(&FS[lq * 4 + reg], elu_f(outv[ct * 4 + reg]) * lw);
        }
        for (int idx = t; idx < 16 * 128; idx += 256) {
            int r = idx >> 7, cc = idx & 127;
            atomicAdd(&FS[16 + r], bf2f(a.FEB0[(size_t)(rbase + r) * F + cc]) * a.FgW2[2 * cc]);
        }
        __syncthreads();
        if (t < 16) {
            int rg = rbase + t;
            float base = a.Finp[rg * 3 + 0];
            float sg = FS[16 + t] + a.Fgb2[0] + base;
            float sl = FS[t] + a.Flb2[0] + base;
            float wg = 1.f / (1.f + __expf(-sg));
            a.Fout[rg] = sg;
            a.Fout[16384 + rg] = sl;
            a.Fout[32768 + rg] = wg * sg + (1.f - wg) * sl;
        }
    }
}

__global__ __launch_bounds__(256)
void dual_layer(LArgs A, LArgs B, int nA) {
    __shared__ ushort SS[NR * SPAD];
    __shared__ float FS[64];
    bool isA = (int)blockIdx.x < nA;
    const LArgs& a = isA ? A : B;
    int blk = isA ? blockIdx.x : blockIdx.x - nA;
    layer_body(a, blk, SS, FS);
}

// ---------------- fused avg block (s1+s2 in one dispatch) ----------------
// Cross-block data through the in-kernel barrier is ONLY the 8x128 atomicAdd
// accumulator (device-coherent). s1's per-row output stays in LDS (transposed
// to A-frag layout). All blocks guaranteed co-resident: launch_bounds(256,8)
// => 8 blocks/CU => capacity 2048 >= max grid (1024 local + <=1024 global).
// POLL IS RELAXED: acquire-per-poll invalidates caches (R10: 27MB writeback
// storm, 160us dispatches). Post-barrier reads of accmid are atomic loads
// (coherence point) so no acquire ordering is needed anywhere on the consumer.
struct AvgArgs {
    const ushort* EA;        // LE1 in (elu of prev layer)
    ushort* EAOUT;           // LE1 out (elu of s2 out)
    const ushort* LBin;      // LB residual in
    ushort* LBout;           // LB out
    const ushort* W1; const ushort* W2;
    const float* b1; const float* b2;
    const float* accin;      // ACC[i-1] (prev dispatch, plain read ok)
    float* accmid;           // ACC[i]   (this dispatch, atomics)
    const float* den; const float* mask;
    int* cnt;                // per-layer barrier counter
};

__device__ __forceinline__ void avg_fused_body(const AvgArgs& a, int blk, int nLoc,
                                               ushort* SS, ushort* AV) {
    const int t = threadIdx.x;
    const int rbase = blk * NR;
    const int w = t >> 6, l = t & 63;
    const int cl = l & 15, lq = l >> 4;
    const int col0 = w * 32 + cl, col1 = col0 + 16;

    // ---- phase A (s1): x1 = [elu(x), avg0] @ W1 + b1 ----
    if (t < 128) {
        float s = 0.f;
#pragma unroll
        for (int r = 0; r < 8; ++r) s += a.accin[r * 128 + t];
        AV[t] = f2bf(s / a.den[0]);
    }
    short8 afrag[4];
    {
        const ushort* ear = a.EA + (size_t)(rbase + cl) * F + lq * 8;
#pragma unroll
        for (int kt = 0; kt < 4; ++kt) afrag[kt] = *(const short8*)(ear + kt * 32);
    }
    __syncthreads();

    f32x4 accA, accB;
#pragma unroll
    for (int i = 0; i < 4; ++i) { accA[i] = 0.f; accB[i] = 0.f; }
#pragma unroll
    for (int kt = 0; kt < 4; ++kt) {
        short8 b0 = *(const short8*)(a.W1 + (size_t)((((kt * 4 + w) * 2 + 0) * 64 + l) * 8));
        short8 b1 = *(const short8*)(a.W1 + (size_t)((((kt * 4 + w) * 2 + 1) * 64 + l) * 8));
        accA = __builtin_amdgcn_mfma_f32_16x16x32_bf16(afrag[kt], b0, accA, 0, 0, 0);
        accB = __builtin_amdgcn_mfma_f32_16x16x32_bf16(afrag[kt], b1, accB, 0, 0, 0);
        short8 aa = *(const short8*)(&AV[lq * 8] + kt * 32);
        short8 c0 = *(const short8*)(a.W1 + 16384 + (size_t)((((kt * 4 + w) * 2 + 0) * 64 + l) * 8));
        short8 c1 = *(const short8*)(a.W1 + 16384 + (size_t)((((kt * 4 + w) * 2 + 1) * 64 + l) * 8));
        accA = __builtin_amdgcn_mfma_f32_16x16x32_bf16(aa, c0, accA, 0, 0, 0);
        accB = __builtin_amdgcn_mfma_f32_16x16x32_bf16(aa, c1, accB, 0, 0, 0);
    }
    {
        const float bv0 = a.b1[col0], bv1 = a.b1[col1];
        float p0 = 0.f, p1 = 0.f;
#pragma unroll
        for (int reg = 0; reg < 4; ++reg) {
            int r = lq * 4 + reg;
            float e0 = elu_f(accA[reg] + bv0);
            float e1 = elu_f(accB[reg] + bv1);
            float mk = a.mask[rbase + r];
            p0 += e0 * mk; p1 += e1 * mk;
            SS[r * SPAD + col0] = f2bf(e0);   // transpose tile: [row][col]
            SS[r * SPAD + col1] = f2bf(e1);
        }
        p0 += __shfl_xor(p0, 16, 64); p0 += __shfl_xor(p0, 32, 64);
        p1 += __shfl_xor(p1, 16, 64); p1 += __shfl_xor(p1, 32, 64);
        if (l < 16) {
            atomicAdd(a.accmid + (blk & 7) * 128 + w * 32 + l, p0);
            atomicAdd(a.accmid + (blk & 7) * 128 + w * 32 + 16 + l, p1);
        }
    }

    // ---- barrier: only accmid (atomics) crosses; RELAXED poll ----
    __syncthreads();
    if (t == 0) {
        __hip_atomic_fetch_add(a.cnt, 1, __ATOMIC_ACQ_REL, __HIP_MEMORY_SCOPE_AGENT);
        while (__hip_atomic_load(a.cnt, __ATOMIC_RELAXED, __HIP_MEMORY_SCOPE_AGENT) < nLoc)
            __builtin_amdgcn_s_sleep(16);
    }
    __syncthreads();

    // ---- phase B (s2): x2 = [elu(x1), avg1] @ W2 + b2 + LB ----
    if (t < 128) {
        float s = 0.f;
#pragma unroll
        for (int r = 0; r < 8; ++r)
            s += __hip_atomic_load(a.accmid + r * 128 + t, __ATOMIC_RELAXED,
                                   __HIP_MEMORY_SCOPE_AGENT);
        AV[t] = f2bf(s / a.den[0]);
    }
    short8 af2[4];
    {
        const ushort* esr = &SS[cl * SPAD + lq * 8];
#pragma unroll
        for (int kt = 0; kt < 4; ++kt) af2[kt] = *(const short8*)(esr + kt * 32);
    }
    __syncthreads();

#pragma unroll
    for (int i = 0; i < 4; ++i) { accA[i] = 0.f; accB[i] = 0.f; }
#pragma unroll
    for (int kt = 0; kt < 4; ++kt) {
        short8 b0 = *(const short8*)(a.W2 + (size_t)((((kt * 4 + w) * 2 + 0) * 64 + l) * 8));
        short8 b1 = *(const short8*)(a.W2 + (size_t)((((kt * 4 + w) * 2 + 1) * 64 + l) * 8));
        accA = __builtin_amdgcn_mfma_f32_16x16x32_bf16(af2[kt], b0, accA, 0, 0, 0);
        accB = __builtin_amdgcn_mfma_f32_16x16x32_bf16(af2[kt], b1, accB, 0, 0, 0);
        short8 aa = *(const short8*)(&AV[lq * 8] + kt * 32);
        short8 c0 = *(const short8*)(a.W2 + 16384 + (size_t)((((kt * 4 + w) * 2 + 0) * 64 + l) * 8));
        short8 c1 = *(const short8*)(a.W2 + 16384 + (size_t)((((kt * 4 + w) * 2 + 1) * 64 + l) * 8));
        accA = __builtin_amdgcn_mfma_f32_16x16x32_bf16(aa, c0, accA, 0, 0, 0);
        accB = __builtin_amdgcn_mfma_f32_16x16x32_bf16(aa, c1, accB, 0, 0, 0);
    }
    {
        const float bv0 = a.b2[col0], bv1 = a.b2[col1];
#pragma unroll
        for (int reg = 0; reg < 4; ++reg) {
            int r = lq * 4 + reg;
            size_t rg = (size_t)(rbase + r);
            float v0 = accA[reg] + bv0 + bf2f(a.LBin[rg * F + col0]);
            float v1 = accB[reg] + bv1 + bf2f(a.LBin[rg * F + col1]);
            a.LBout[rg * F + col0] = f2bf(v0);
            a.LBout[rg * F + col1] = f2bf(v1);
            a.EAOUT[rg * F + col0] = f2bf(elu_f(v0));
            a.EAOUT[rg * F + col1] = f2bf(elu_f(v1));
        }
    }
}

__global__ __launch_bounds__(256, 8)
void dual_avg(LArgs G, AvgArgs V, int nA, int nLoc) {
    __shared__ ushort SS[NR * SPAD];
    __shared__ ushort AV[128];
    __shared__ float FS[64];
    if ((int)blockIdx.x < nA) layer_body(G, blockIdx.x, SS, FS);
    else avg_fused_body(V, (int)blockIdx.x - nA, nLoc, SS, AV);
}

extern "C" void kernel_launch(void* const* d_in, const int* in_sizes, int n_in,
                              void* d_out, int out_size, void* d_ws, size_t ws_size,
                              hipStream_t stream) {
    (void)in_sizes; (void)n_in; (void)out_size; (void)ws_size;
    const float* inputs = (const float*)d_in[0];
    const float* mask1  = (const float*)d_in[2];
    const int*   lrows[5] = {(const int*)d_in[3], (const int*)d_in[6], (const int*)d_in[9],
                             (const int*)d_in[12], (const int*)d_in[15]};
    const int*   lcols[5] = {(const int*)d_in[4], (const int*)d_in[7], (const int*)d_in[10],
                             (const int*)d_in[13], (const int*)d_in[16]};
    const float* lvals[5] = {(const float*)d_in[5], (const float*)d_in[8], (const float*)d_in[11],
                             (const float*)d_in[14], (const float*)d_in[17]};
    const float* gW1 = (const float*)d_in[18];
    const float* gb1 = (const float*)d_in[19];
    const float* gdW = (const float*)d_in[20];
    const float* gdb = (const float*)d_in[21];
    const float* glW = (const float*)d_in[22];
    const float* glb = (const float*)d_in[23];
    const float* guW = (const float*)d_in[24];
    const float* gub = (const float*)d_in[25];
    const float* gW2 = (const float*)d_in[26];
    const float* gb2 = (const float*)d_in[27];
    const float* lW1 = (const float*)d_in[28];
    const float* lb1 = (const float*)d_in[29];
    const float* lrW = (const float*)d_in[30];
    const float* lrb = (const float*)d_in[31];
    const float* lW2 = (const float*)d_in[32];
    const float* lb2 = (const float*)d_in[33];
    float* out = (float*)d_out;

    const int N = 16384;
    const int nlev[5] = {2048, 4096, 8192, 16384, 16384};

    char* ws = (char*)d_ws;
    size_t off = 0;
    auto alloc = [&](size_t bytes) -> char* {
        char* p = ws + off;
        off = (off + bytes + 255) & ~(size_t)255;
        return p;
    };
    // bf16 residual / skip / pool streams
    ushort* BUF0 = (ushort*)alloc((size_t)N * F * 2);
    ushort* GU2  = (ushort*)alloc((size_t)N * F * 2);
    ushort* G2   = (ushort*)alloc((size_t)N * F * 2);
    ushort* D8   = (ushort*)alloc((size_t)8192 * F * 2);
    ushort* D4   = (ushort*)alloc((size_t)4096 * F * 2);
    ushort* D2   = (ushort*)alloc((size_t)2048 * F * 2);
    ushort* LB   = (ushort*)alloc((size_t)N * F * 2);
    ushort* EB0 = (ushort*)alloc((size_t)N * F * 2);
    ushort* EG1 = (ushort*)alloc((size_t)N * F * 2);
    ushort* EG2 = (ushort*)alloc((size_t)N * F * 2);
    ushort* ED8 = (ushort*)alloc((size_t)8192 * F * 2);
    ushort* ED4 = (ushort*)alloc((size_t)4096 * F * 2);
    ushort* ED2 = (ushort*)alloc((size_t)2048 * F * 2);
    ushort* LE1 = (ushort*)alloc((size_t)N * F * 2);
    ushort* LE2 = (ushort*)alloc((size_t)N * F * 2);
    int* rp[5];
    for (int i = 0; i < 5; ++i) rp[i] = (int*)alloc((size_t)(nlev[i] + 1) * 4);
    float* ACC = (float*)alloc((size_t)14 * 8 * 128 * 4);   // 8 replicas per slot
    float* DEN = (float*)alloc(4);
    int* CNT = (int*)alloc((size_t)7 * 16 * 4);
    ushort* Pd = (ushort*)alloc((size_t)12 * 16384 * 2);
    ushort* Pl = (ushort*)alloc((size_t)4  * 16384 * 2);
    ushort* Pu = (ushort*)alloc((size_t)12 * 16384 * 2);
    ushort* Pr = (ushort*)alloc((size_t)60 * 16384 * 2);

    SetupArgs sa;
    sa.ws0 = gdW; sa.ws1 = glW; sa.ws2 = guW; sa.ws3 = lrW;
    sa.wd0 = Pd;  sa.wd1 = Pl;  sa.wd2 = Pu;  sa.wd3 = Pr;
    sa.rows0 = lrows[0]; sa.rows1 = lrows[1]; sa.rows2 = lrows[2];
    sa.rows3 = lrows[3]; sa.rows4 = lrows[4];
    sa.rp0 = rp[0]; sa.rp1 = rp[1]; sa.rp2 = rp[2]; sa.rp3 = rp[3]; sa.rp4 = rp[4];
    sa.mask = mask1; sa.den = DEN; sa.acc = ACC; sa.cnt = CNT;
    sa.in = inputs; sa.Wg = gW1; sa.bg = gb1; sa.Wl = lW1; sa.bl = lb1;
    sa.og = BUF0; sa.eg = EB0; sa.ol = LB; sa.el = LE1;
    setup_conv1<<<274 + 8192, 256, 0, stream>>>(sa);

    const size_t PSZ = 2 * 16384;   // packed bf16 stride per sub-layer (2 halves)

    auto mkL = [&](const ushort* ea, const ushort* res, ushort* o, ushort* eao,
                   int lv, const ushort* wp, const float* bias, float* accout,
                   int epi, ushort* eo, ushort* ee, const ushort* skip,
                   const float* accin, int fin) {
        LArgs x;
        x.EA = ea; x.RES = res; x.OUT = o; x.EAOUT = eao;
        x.rowptr = (lv >= 0) ? rp[lv] : nullptr;
        x.cols = (lv >= 0) ? lcols[lv] : nullptr;
        x.vals = (lv >= 0) ? lvals[lv] : nullptr;
        x.Wp = wp; x.bias = bias;
        x.accin = accin; x.den = DEN;
        x.mask = mask1; x.accout = accout;
        x.EO = eo; x.EE = ee; x.SKIP = skip; x.epi = epi;
        x.fin = fin;
        x.Finp = inputs; x.FEB0 = EB0;
        x.FgW2 = gW2; x.Fgb2 = gb2; x.FlW2 = lW2; x.Flb2 = lb2; x.Fout = out;
        return x;
    };

    // ---- global branch slots (pool/upadd fused into sub2 epilogues) ----
    LArgs gs[14]; int gn[14];
    gs[0]  = mkL(EB0, 0, 0, EG1, 3, Pd + 0 * PSZ, gdb + 0,   0, 0, 0, 0, 0, 0, 0);  gn[0]  = 16384;
    gs[1]  = mkL(EG1, BUF0, 0, 0, 3, Pd + 1 * PSZ, gdb + 128, 0, 1, D8, ED8, 0, 0, 0); gn[1] = 16384;
    gs[2]  = mkL(ED8, 0, 0, EG1, 2, Pd + 2 * PSZ, gdb + 256, 0, 0, 0, 0, 0, 0, 0);  gn[2]  = 8192;
    gs[3]  = mkL(EG1, D8, 0, 0, 2, Pd + 3 * PSZ, gdb + 384, 0, 1, D4, ED4, 0, 0, 0); gn[3]  = 8192;
    gs[4]  = mkL(ED4, 0, 0, EG1, 1, Pd + 4 * PSZ, gdb + 512, 0, 0, 0, 0, 0, 0, 0);  gn[4]  = 4096;
    gs[5]  = mkL(EG1, D4, 0, 0, 1, Pd + 5 * PSZ, gdb + 640, 0, 1, D2, ED2, 0, 0, 0); gn[5]  = 4096;
    gs[6]  = mkL(ED2, 0, 0, EG1, 0, Pl + 0 * PSZ, glb + 0,   0, 0, 0, 0, 0, 0, 0);  gn[6]  = 2048;
    gs[7]  = mkL(EG1, D2, 0, 0, 0, Pl + 1 * PSZ, glb + 128, 0, 2, GU2, EG2, D4, 0, 0); gn[7] = 2048;
    gs[8]  = mkL(EG2, 0, 0, EG1, 1, Pu + 0 * PSZ, gub + 0,   0, 0, 0, 0, 0, 0, 0);  gn[8]  = 4096;
    gs[9]  = mkL(EG1, GU2, 0, 0, 1, Pu + 1 * PSZ, gub + 128, 0, 2, G2, EG2, D8, 0, 0); gn[9] = 4096;
    gs[10] = mkL(EG2, 0, 0, EG1, 2, Pu + 2 * PSZ, gub + 256, 0, 0, 0, 0, 0, 0, 0);  gn[10] = 8192;
    gs[11] = mkL(EG1, G2, 0, 0, 2, Pu + 3 * PSZ, gub + 384, 0, 2, GU2, EG2, BUF0, 0, 0); gn[11] = 8192;
    gs[12] = mkL(EG2, 0, 0, EG1, 3, Pu + 4 * PSZ, gub + 512, 0, 0, 0, 0, 0, 0, 0);  gn[12] = 16384;
    gs[13] = mkL(EG1, GU2, 0, EB0, 3, Pu + 5 * PSZ, gub + 640, 0, 0, 0, 0, 0, 0, 0); gn[13] = 16384;

    const int NB_LOC = N / NR;   // 1024 local blocks
    int gi = 0;
    auto launchLap = [&](const LArgs& loc) {
        if (gi < 14) {
            int na = gn[gi] / NR;
            dual_layer<<<na + NB_LOC, 256, 0, stream>>>(gs[gi], loc, na);
            ++gi;
        } else {
            dual_layer<<<NB_LOC, 256, 0, stream>>>(loc, loc, NB_LOC);
        }
    };

    for (int i = 0; i < 15; ++i) {
        const ushort* P1 = Pr + (size_t)(2 * i) * PSZ;
        const ushort* P2 = Pr + (size_t)(2 * i + 1) * PSZ;
        const float* b1 = lrb + (size_t)i * 256;
        const float* b2 = b1 + 128;
        if ((i & 1) == 0) {   // lap block on L (level 4)
            LArgs s1 = mkL(LE1, 0, 0, LE2, 4, P1, b1, 0, 0, 0, 0, 0, 0, 0);
            float* accout = (i <= 12) ? (ACC + (size_t)i * 1024) : nullptr;
            int fin = (i == 14);
            LArgs s2 = mkL(LE2, LB, fin ? nullptr : LB, fin ? nullptr : LE1, 4,
                           P2, b2, accout, 0, 0, 0, 0, 0, fin);
            launchLap(s1);
            launchLap(s2);
        } else {              // avg block: fused s1+s2, atomics-only in-kernel barrier
            AvgArgs v;
            v.EA = LE1; v.EAOUT = LE1;
            v.LBin = LB; v.LBout = LB;
            v.W1 = P1; v.W2 = P2;
            v.b1 = b1; v.b2 = b2;
            v.accin = ACC + (size_t)(i - 1) * 1024;
            v.accmid = ACC + (size_t)i * 1024;
            v.den = DEN; v.mask = mask1;
            v.cnt = CNT + (size_t)(i >> 1) * 16;
            if (gi < 14) {
                int na = gn[gi] / NR;
                dual_avg<<<na + NB_LOC, 256, 0, stream>>>(gs[gi], v, na, NB_LOC);
                ++gi;
            } else {
                dual_avg<<<NB_LOC, 256, 0, stream>>>(gs[0], v, 0, NB_LOC);
            }
        }
    }
}

// Round 12
// 622.245 us; speedup vs baseline: 2.1199x; 1.8227x over previous
//
#include <hip/hip_runtime.h>

#define F 128
#define SPAD 136      // LDS stride (ushorts) for gather S tile
#define NR 16         // rows per tile (16x16 MFMA path)

typedef __attribute__((ext_vector_type(8))) short short8;
typedef __attribute__((ext_vector_type(4))) float f32x4;
typedef unsigned long long ull;

__device__ __forceinline__ float elu_f(float x) {
    return x > 0.f ? x : __expf(x) - 1.f;
}
__device__ __forceinline__ ushort f2bf(float x) {   // fp32 -> bf16 RNE
    unsigned u = __float_as_uint(x);
    u = (u + 0x7FFFu + ((u >> 16) & 1u)) >> 16;
    return (ushort)u;
}
__device__ __forceinline__ float bf2f(ushort u) {
    return __uint_as_float((unsigned)u << 16);
}
__device__ __forceinline__ void bfma8(float* a, float v, short8 u) {
#pragma unroll
    for (int i = 0; i < 8; ++i) a[i] += v * bf2f((ushort)u[i]);
}

// ---------------- fused setup + conv1 ----------------
// blocks 0..87: weight pack (16x16 frag layout); 88..272: rowptr; 273: denom+ACC zero;
// 274..8465: conv1
struct SetupArgs {
    const float* ws0; const float* ws1; const float* ws2; const float* ws3;
    ushort* wd0; ushort* wd1; ushort* wd2; ushort* wd3;
    const int* rows0; const int* rows1; const int* rows2; const int* rows3; const int* rows4;
    int* rp0; int* rp1; int* rp2; int* rp3; int* rp4;
    const float* mask; float* den; float* acc;   // acc: 14*8*128 floats
    const float* in; const float* Wg; const float* bg; const float* Wl; const float* bl;
    ushort* og; ushort* eg; ushort* ol; ushort* el;   // bf16 residual streams
};

__global__ __launch_bounds__(256) void setup_conv1(SetupArgs s) {
    __shared__ ushort tile[16384];
    int b = blockIdx.x, t = threadIdx.x;
    if (b >= 274) {
        int id = (b - 274) * 256 + t;
        int r = id >> 7, c = id & 127;
        float x0 = s.in[r * 3 + 0], x1 = s.in[r * 3 + 1], x2 = s.in[r * 3 + 2];
        float g = x0 * s.Wg[c] + x1 * s.Wg[F + c] + x2 * s.Wg[2 * F + c] + s.bg[c];
        float lo = x0 * s.Wl[c] + x1 * s.Wl[F + c] + x2 * s.Wl[2 * F + c] + s.bl[c];
        s.og[id] = f2bf(g);  s.eg[id] = f2bf(elu_f(g));
        s.ol[id] = f2bf(lo); s.el[id] = f2bf(elu_f(lo));
    } else if (b < 88) {
        const float* src; ushort* dst; int lb;
        if (b < 12)      { src = s.ws0; dst = s.wd0; lb = b; }
        else if (b < 16) { src = s.ws1; dst = s.wd1; lb = b - 12; }
        else if (b < 28) { src = s.ws2; dst = s.wd2; lb = b - 16; }
        else             { src = s.ws3; dst = s.wd3; lb = b - 28; }
        src += (size_t)lb * 16384; dst += (size_t)lb * 16384;
        for (int idx = t; idx < 16384; idx += 256) {
            int k = idx >> 7, nn = idx & 127;
            // 16x16x32 B-frag: lane = lq*16 + col, elem j; k = kt*32 + lq*8 + j
            int kt = k >> 5, lq = (k >> 3) & 3, j = k & 7;
            int wv = nn >> 5, ct = (nn >> 4) & 1, cc = nn & 15;
            tile[((((kt * 4 + wv) * 2 + ct) * 64 + lq * 16 + cc)) * 8 + j] = f2bf(src[idx]);
        }
        __syncthreads();
        ull* td = (ull*)dst; const ull* ts = (const ull*)tile;
        for (int i = t; i < 4096; i += 256) td[i] = ts[i];
    } else if (b < 273) {
        int tid = (b - 88) * 256 + t;
        const int ns[5] = {2048, 4096, 8192, 16384, 16384};
        const int es[5] = {16384, 32768, 65536, 131072, 131072};
        const int* rowsA[5] = {s.rows0, s.rows1, s.rows2, s.rows3, s.rows4};
        int* rpA[5] = {s.rp0, s.rp1, s.rp2, s.rp3, s.rp4};
        int base = 0;
        for (int lv = 0; lv < 5; ++lv) {
            int cnt = ns[lv] + 1;
            if (tid < base + cnt) {
                int r = tid - base;
                const int* rows = rowsA[lv]; int e = es[lv];
                int lo = 0, hi = e;
                while (lo < hi) { int mid = (lo + hi) >> 1; if (rows[mid] < r) lo = mid + 1; else hi = mid; }
                rpA[lv][r] = lo;
                return;
            }
            base += cnt;
        }
    } else {
        __shared__ float red[256];
        float ssum = 0.f;
        for (int i = t; i < 16384; i += 256) ssum += s.mask[i];
        red[t] = ssum; __syncthreads();
        for (int st = 128; st > 0; st >>= 1) { if (t < st) red[t] += red[t + st]; __syncthreads(); }
        if (t == 0) s.den[0] = red[0];
        for (int i = t; i < 14336; i += 256) s.acc[i] = 0.f;
    }
}

// ---------------- unified layer ----------------
struct LArgs {
    const ushort* EA; const ushort* RES; ushort* OUT; ushort* EAOUT;
    const int* rowptr; const int* cols; const float* vals;
    const ushort* Wp; const float* bias;
    const float* accin; const float* den;    // avg mode: 8-replica ACC of prev slot
    const float* mask; float* accout;        // 8-replica out
    ushort* EO; ushort* EE; const ushort* SKIP;
    int epi;  // 0 none, 1 maxpool2, 2 repeat2+skip
    int fin;  // final-head epilogue
    const float* Finp; const ushort* FEB0;
    const float* FgW2; const float* Fgb2; const float* FlW2; const float* Flb2;
    float* Fout;
};

__device__ __forceinline__ void layer_body(const LArgs& a, int blk, ushort* SS, float* FS) {
    const int t = threadIdx.x;
    const int rbase = blk * NR;
    const int w = t >> 6, l = t & 63;
    const int cl = l & 15, lq = l >> 4;       // col-in-tile / K-octet selector
    const bool lap = (a.rowptr != nullptr);
    const bool avg = (a.accin != nullptr);

    if (lap) {
        // 16 lanes per row, 16 concurrent rows/block; lane-parallel cols/vals
        // (one coalesced load covers 16 edges) + full-window issue (1 load/edge/lane).
        // Gather loads are NONTEMPORAL: each line has ~1 consumer per XCD, so
        // caching it evicts the reused resident set (weights/cols/vals) for nothing.
        const int grp = t >> 4, l16 = t & 15;
        const int lbase = l & ~15;            // group base lane within wave
        const short8* EA8 = (const short8*)a.EA;
        const int row = rbase + grp;
        const int e0 = a.rowptr[row], e1 = a.rowptr[row + 1];
        float acc0[8];
#pragma unroll
        for (int i = 0; i < 8; ++i) acc0[i] = 0.f;
        int myc = 0; float myv = 0.f;
        if (e0 + l16 < e1) { myc = a.cols[e0 + l16]; myv = a.vals[e0 + l16]; }
#pragma unroll 1
        for (int base = e0; base < e1; base += 16) {
            int nc = 0; float nv = 0.f;
            {
                int en = base + 16 + l16;
                if (en < e1) { nc = a.cols[en]; nv = a.vals[en]; }
            }
#pragma unroll
            for (int half = 0; half < 2; ++half) {
                int hb = base + half * 8;
                if (hb < e1) {
                    int cnt = e1 - hb; if (cnt > 8) cnt = 8;
                    int cc[8];
#pragma unroll
                    for (int k = 0; k < 8; ++k) cc[k] = __shfl(myc, lbase + half * 8 + k, 64);
                    short8 ua[8];
#pragma unroll
                    for (int k = 0; k < 8; ++k)
                        if (k < cnt) ua[k] = __builtin_nontemporal_load(
                                                 &EA8[(size_t)cc[k] * 16 + l16]);
#pragma unroll
                    for (int k = 0; k < 8; ++k)
                        if (k < cnt) {
                            float v = __shfl(myv, lbase + half * 8 + k, 64);
                            bfma8(acc0, v, ua[k]);
                        }
                }
            }
            myc = nc; myv = nv;
        }
        short8 s0;
#pragma unroll
        for (int i = 0; i < 8; ++i) s0[i] = (short)f2bf(acc0[i]);
        *(short8*)(&SS[grp * SPAD + l16 * 8]) = s0;
        __syncthreads();
    } else if (avg) {
        // avg vector (8-replica sum / denom) as a broadcast bf16 A-row in LDS
        if (t < 128) {
            float s = 0.f;
#pragma unroll
            for (int r = 0; r < 8; ++r) s += a.accin[r * 128 + t];
            SS[t] = f2bf(s / a.den[0]);
        }
        __syncthreads();
    }

    // dense-half A-fragments from EA global: row = rbase+cl, k = kt*32 + lq*8 + j
    short8 afrag[4];
    {
        const ushort* ear = a.EA + (size_t)(rbase + cl) * F + lq * 8;
#pragma unroll
        for (int kt = 0; kt < 4; ++kt) afrag[kt] = *(const short8*)(ear + kt * 32);
    }

    f32x4 accA, accB;   // ct = 0, 1 (named: avoid runtime-indexed regs)
#pragma unroll
    for (int i = 0; i < 4; ++i) { accA[i] = 0.f; accB[i] = 0.f; }
#pragma unroll
    for (int kt = 0; kt < 4; ++kt) {
        short8 b0 = *(const short8*)(a.Wp + (size_t)((((kt * 4 + w) * 2 + 0) * 64 + l) * 8));
        short8 b1 = *(const short8*)(a.Wp + (size_t)((((kt * 4 + w) * 2 + 1) * 64 + l) * 8));
        accA = __builtin_amdgcn_mfma_f32_16x16x32_bf16(afrag[kt], b0, accA, 0, 0, 0);
        accB = __builtin_amdgcn_mfma_f32_16x16x32_bf16(afrag[kt], b1, accB, 0, 0, 0);
    }
    if (lap || avg) {
        const ushort* esr = lap ? &SS[cl * SPAD + lq * 8] : &SS[lq * 8];
#pragma unroll
        for (int kt = 0; kt < 4; ++kt) {
            short8 aa = *(const short8*)(esr + kt * 32);
            short8 b0 = *(const short8*)(a.Wp + 16384 + (size_t)((((kt * 4 + w) * 2 + 0) * 64 + l) * 8));
            short8 b1 = *(const short8*)(a.Wp + 16384 + (size_t)((((kt * 4 + w) * 2 + 1) * 64 + l) * 8));
            accA = __builtin_amdgcn_mfma_f32_16x16x32_bf16(aa, b0, accA, 0, 0, 0);
            accB = __builtin_amdgcn_mfma_f32_16x16x32_bf16(aa, b1, accB, 0, 0, 0);
        }
    }

    // C/D: col = cl (+ct*16), row = lq*4 + reg
    const int col0 = w * 32 + cl, col1 = w * 32 + 16 + cl;
    const float bv0 = a.bias[col0], bv1 = a.bias[col1];
    float outv[8];     // [ct*4 + reg]
#pragma unroll
    for (int reg = 0; reg < 4; ++reg) {
        int r = lq * 4 + reg;
        size_t rg = (size_t)(rbase + r);
        float v0 = accA[reg] + bv0;
        float v1 = accB[reg] + bv1;
        if (a.RES) { v0 += bf2f(a.RES[rg * F + col0]); v1 += bf2f(a.RES[rg * F + col1]); }
        outv[reg] = v0; outv[4 + reg] = v1;
        if (a.OUT) { a.OUT[rg * F + col0] = f2bf(v0); a.OUT[rg * F + col1] = f2bf(v1); }
        if (a.EAOUT) { a.EAOUT[rg * F + col0] = f2bf(elu_f(v0)); a.EAOUT[rg * F + col1] = f2bf(elu_f(v1)); }
    }
    if (a.accout) {
        float p0 = 0.f, p1 = 0.f;
#pragma unroll
        for (int reg = 0; reg < 4; ++reg) {
            float mk = a.mask[rbase + lq * 4 + reg];
            p0 += elu_f(outv[reg]) * mk;
            p1 += elu_f(outv[4 + reg]) * mk;
        }
        p0 += __shfl_xor(p0, 16, 64); p0 += __shfl_xor(p0, 32, 64);
        p1 += __shfl_xor(p1, 16, 64); p1 += __shfl_xor(p1, 32, 64);
        if (l < 16) {
            atomicAdd(a.accout + (blk & 7) * 128 + w * 32 + l, p0);
            atomicAdd(a.accout + (blk & 7) * 128 + w * 32 + 16 + l, p1);
        }
    }
    if (a.epi == 1) {          // fused maxpool2 (pairs lane-local: rows lq*4+{0..3})
        int rb2 = rbase >> 1;
#pragma unroll
        for (int ct = 0; ct < 2; ++ct)
#pragma unroll
            for (int e2 = 0; e2 < 2; ++e2) {
                float pv = fmaxf(outv[ct * 4 + e2 * 2], outv[ct * 4 + e2 * 2 + 1]);
                size_t idx = (size_t)(rb2 + lq * 2 + e2) * F + (ct ? col1 : col0);
                a.EO[idx] = f2bf(pv);
                a.EE[idx] = f2bf(elu_f(pv));
            }
    } else if (a.epi == 2) {   // fused repeat2 + skip add
#pragma unroll
        for (int ct = 0; ct < 2; ++ct)
#pragma unroll
            for (int reg = 0; reg < 4; ++reg) {
                int r = lq * 4 + reg;
                size_t R0 = (size_t)(2 * (rbase + r)) * F + (ct ? col1 : col0);
                float v0 = outv[ct * 4 + reg] + bf2f(a.SKIP[R0]);
                float v1 = outv[ct * 4 + reg] + bf2f(a.SKIP[R0 + F]);
                a.EO[R0] = f2bf(v0);     a.EO[R0 + F] = f2bf(v1);
                a.EE[R0] = f2bf(elu_f(v0)); a.EE[R0 + F] = f2bf(elu_f(v1));
            }
    }
    if (a.fin) {               // fused final head (16 rows/block)
        __syncthreads();
        if (t < 32) FS[t] = 0.f;
        __syncthreads();
#pragma unroll
        for (int ct = 0; ct < 2; ++ct) {
            float lw = a.FlW2[ct ? col1 : col0];
#pragma unroll
            for (int reg = 0; reg < 4; ++reg)
                atomicAdd(&FS[lq * 4 + reg], elu_f(outv[ct * 4 + reg]) * lw);
        }
        for (int idx = t; idx < 16 * 128; idx += 256) {
            int r = idx >> 7, cc = idx & 127;
            atomicAdd(&FS[16 + r], bf2f(a.FEB0[(size_t)(rbase + r) * F + cc]) * a.FgW2[2 * cc]);
        }
        __syncthreads();
        if (t < 16) {
            int rg = rbase + t;
            float base = a.Finp[rg * 3 + 0];
            float sg = FS[16 + t] + a.Fgb2[0] + base;
            float sl = FS[t] + a.Flb2[0] + base;
            float wg = 1.f / (1.f + __expf(-sg));
            a.Fout[rg] = sg;
            a.Fout[16384 + rg] = sl;
            a.Fout[32768 + rg] = wg * sg + (1.f - wg) * sl;
        }
    }
}

__global__ __launch_bounds__(256)
void dual_layer(LArgs A, LArgs B, int nA) {
    __shared__ ushort SS[NR * SPAD];
    __shared__ float FS[64];
    bool isA = (int)blockIdx.x < nA;
    const LArgs& a = isA ? A : B;
    int blk = isA ? blockIdx.x : blockIdx.x - nA;
    layer_body(a, blk, SS, FS);
}

extern "C" void kernel_launch(void* const* d_in, const int* in_sizes, int n_in,
                              void* d_out, int out_size, void* d_ws, size_t ws_size,
                              hipStream_t stream) {
    (void)in_sizes; (void)n_in; (void)out_size; (void)ws_size;
    const float* inputs = (const float*)d_in[0];
    const float* mask1  = (const float*)d_in[2];
    const int*   lrows[5] = {(const int*)d_in[3], (const int*)d_in[6], (const int*)d_in[9],
                             (const int*)d_in[12], (const int*)d_in[15]};
    const int*   lcols[5] = {(const int*)d_in[4], (const int*)d_in[7], (const int*)d_in[10],
                             (const int*)d_in[13], (const int*)d_in[16]};
    const float* lvals[5] = {(const float*)d_in[5], (const float*)d_in[8], (const float*)d_in[11],
                             (const float*)d_in[14], (const float*)d_in[17]};
    const float* gW1 = (const float*)d_in[18];
    const float* gb1 = (const float*)d_in[19];
    const float* gdW = (const float*)d_in[20];
    const float* gdb = (const float*)d_in[21];
    const float* glW = (const float*)d_in[22];
    const float* glb = (const float*)d_in[23];
    const float* guW = (const float*)d_in[24];
    const float* gub = (const float*)d_in[25];
    const float* gW2 = (const float*)d_in[26];
    const float* gb2 = (const float*)d_in[27];
    const float* lW1 = (const float*)d_in[28];
    const float* lb1 = (const float*)d_in[29];
    const float* lrW = (const float*)d_in[30];
    const float* lrb = (const float*)d_in[31];
    const float* lW2 = (const float*)d_in[32];
    const float* lb2 = (const float*)d_in[33];
    float* out = (float*)d_out;

    const int N = 16384;
    const int nlev[5] = {2048, 4096, 8192, 16384, 16384};

    char* ws = (char*)d_ws;
    size_t off = 0;
    auto alloc = [&](size_t bytes) -> char* {
        char* p = ws + off;
        off = (off + bytes + 255) & ~(size_t)255;
        return p;
    };
    // bf16 residual / skip / pool streams
    ushort* BUF0 = (ushort*)alloc((size_t)N * F * 2);
    ushort* GU2  = (ushort*)alloc((size_t)N * F * 2);
    ushort* G2   = (ushort*)alloc((size_t)N * F * 2);
    ushort* D8   = (ushort*)alloc((size_t)8192 * F * 2);
    ushort* D4   = (ushort*)alloc((size_t)4096 * F * 2);
    ushort* D2   = (ushort*)alloc((size_t)2048 * F * 2);
    ushort* LB   = (ushort*)alloc((size_t)N * F * 2);
    ushort* EB0 = (ushort*)alloc((size_t)N * F * 2);
    ushort* EG1 = (ushort*)alloc((size_t)N * F * 2);
    ushort* EG2 = (ushort*)alloc((size_t)N * F * 2);
    ushort* ED8 = (ushort*)alloc((size_t)8192 * F * 2);
    ushort* ED4 = (ushort*)alloc((size_t)4096 * F * 2);
    ushort* ED2 = (ushort*)alloc((size_t)2048 * F * 2);
    ushort* LE1 = (ushort*)alloc((size_t)N * F * 2);
    ushort* LE2 = (ushort*)alloc((size_t)N * F * 2);
    int* rp[5];
    for (int i = 0; i < 5; ++i) rp[i] = (int*)alloc((size_t)(nlev[i] + 1) * 4);
    float* ACC = (float*)alloc((size_t)14 * 8 * 128 * 4);   // 8 replicas per slot
    float* DEN = (float*)alloc(4);
    ushort* Pd = (ushort*)alloc((size_t)12 * 16384 * 2);
    ushort* Pl = (ushort*)alloc((size_t)4  * 16384 * 2);
    ushort* Pu = (ushort*)alloc((size_t)12 * 16384 * 2);
    ushort* Pr = (ushort*)alloc((size_t)60 * 16384 * 2);

    SetupArgs sa;
    sa.ws0 = gdW; sa.ws1 = glW; sa.ws2 = guW; sa.ws3 = lrW;
    sa.wd0 = Pd;  sa.wd1 = Pl;  sa.wd2 = Pu;  sa.wd3 = Pr;
    sa.rows0 = lrows[0]; sa.rows1 = lrows[1]; sa.rows2 = lrows[2];
    sa.rows3 = lrows[3]; sa.rows4 = lrows[4];
    sa.rp0 = rp[0]; sa.rp1 = rp[1]; sa.rp2 = rp[2]; sa.rp3 = rp[3]; sa.rp4 = rp[4];
    sa.mask = mask1; sa.den = DEN; sa.acc = ACC;
    sa.in = inputs; sa.Wg = gW1; sa.bg = gb1; sa.Wl = lW1; sa.bl = lb1;
    sa.og = BUF0; sa.eg = EB0; sa.ol = LB; sa.el = LE1;
    setup_conv1<<<274 + 8192, 256, 0, stream>>>(sa);

    const size_t PSZ = 2 * 16384;   // packed bf16 stride per sub-layer (2 halves)

    auto mkL = [&](const ushort* ea, const ushort* res, ushort* o, ushort* eao,
                   int lv, const ushort* wp, const float* bias, float* accout,
                   int epi, ushort* eo, ushort* ee, const ushort* skip,
                   const float* accin, int fin) {
        LArgs x;
        x.EA = ea; x.RES = res; x.OUT = o; x.EAOUT = eao;
        x.rowptr = (lv >= 0) ? rp[lv] : nullptr;
        x.cols = (lv >= 0) ? lcols[lv] : nullptr;
        x.vals = (lv >= 0) ? lvals[lv] : nullptr;
        x.Wp = wp; x.bias = bias;
        x.accin = accin; x.den = DEN;
        x.mask = mask1; x.accout = accout;
        x.EO = eo; x.EE = ee; x.SKIP = skip; x.epi = epi;
        x.fin = fin;
        x.Finp = inputs; x.FEB0 = EB0;
        x.FgW2 = gW2; x.Fgb2 = gb2; x.FlW2 = lW2; x.Flb2 = lb2; x.Fout = out;
        return x;
    };

    // ---- global branch slots (pool/upadd fused into sub2 epilogues) ----
    LArgs gs[14]; int gn[14];
    gs[0]  = mkL(EB0, 0, 0, EG1, 3, Pd + 0 * PSZ, gdb + 0,   0, 0, 0, 0, 0, 0, 0);  gn[0]  = 16384;
    gs[1]  = mkL(EG1, BUF0, 0, 0, 3, Pd + 1 * PSZ, gdb + 128, 0, 1, D8, ED8, 0, 0, 0); gn[1] = 16384;
    gs[2]  = mkL(ED8, 0, 0, EG1, 2, Pd + 2 * PSZ, gdb + 256, 0, 0, 0, 0, 0, 0, 0);  gn[2]  = 8192;
    gs[3]  = mkL(EG1, D8, 0, 0, 2, Pd + 3 * PSZ, gdb + 384, 0, 1, D4, ED4, 0, 0, 0); gn[3]  = 8192;
    gs[4]  = mkL(ED4, 0, 0, EG1, 1, Pd + 4 * PSZ, gdb + 512, 0, 0, 0, 0, 0, 0, 0);  gn[4]  = 4096;
    gs[5]  = mkL(EG1, D4, 0, 0, 1, Pd + 5 * PSZ, gdb + 640, 0, 1, D2, ED2, 0, 0, 0); gn[5]  = 4096;
    gs[6]  = mkL(ED2, 0, 0, EG1, 0, Pl + 0 * PSZ, glb + 0,   0, 0, 0, 0, 0, 0, 0);  gn[6]  = 2048;
    gs[7]  = mkL(EG1, D2, 0, 0, 0, Pl + 1 * PSZ, glb + 128, 0, 2, GU2, EG2, D4, 0, 0); gn[7] = 2048;
    gs[8]  = mkL(EG2, 0, 0, EG1, 1, Pu + 0 * PSZ, gub + 0,   0, 0, 0, 0, 0, 0, 0);  gn[8]  = 4096;
    gs[9]  = mkL(EG1, GU2, 0, 0, 1, Pu + 1 * PSZ, gub + 128, 0, 2, G2, EG2, D8, 0, 0); gn[9] = 4096;
    gs[10] = mkL(EG2, 0, 0, EG1, 2, Pu + 2 * PSZ, gub + 256, 0, 0, 0, 0, 0, 0, 0);  gn[10] = 8192;
    gs[11] = mkL(EG1, G2, 0, 0, 2, Pu + 3 * PSZ, gub + 384, 0, 2, GU2, EG2, BUF0, 0, 0); gn[11] = 8192;
    gs[12] = mkL(EG2, 0, 0, EG1, 3, Pu + 4 * PSZ, gub + 512, 0, 0, 0, 0, 0, 0, 0);  gn[12] = 16384;
    gs[13] = mkL(EG1, GU2, 0, EB0, 3, Pu + 5 * PSZ, gub + 640, 0, 0, 0, 0, 0, 0, 0); gn[13] = 16384;

    const int NB_LOC = N / NR;   // 1024 local blocks
    int gi = 0;
    auto launchLap = [&](const LArgs& loc) {
        if (gi < 14) {
            int na = gn[gi] / NR;
            dual_layer<<<na + NB_LOC, 256, 0, stream>>>(gs[gi], loc, na);
            ++gi;
        } else {
            dual_layer<<<NB_LOC, 256, 0, stream>>>(loc, loc, NB_LOC);
        }
    };

    for (int i = 0; i < 15; ++i) {
        const ushort* P1 = Pr + (size_t)(2 * i) * PSZ;
        const ushort* P2 = Pr + (size_t)(2 * i + 1) * PSZ;
        const float* b1 = lrb + (size_t)i * 256;
        const float* b2 = b1 + 128;
        if ((i & 1) == 0) {   // lap block on L (level 4)
            LArgs s1 = mkL(LE1, 0, 0, LE2, 4, P1, b1, 0, 0, 0, 0, 0, 0, 0);
            float* accout = (i <= 12) ? (ACC + (size_t)i * 1024) : nullptr;
            int fin = (i == 14);
            LArgs s2 = mkL(LE2, LB, fin ? nullptr : LB, fin ? nullptr : LE1, 4,
                           P2, b2, accout, 0, 0, 0, 0, 0, fin);
            launchLap(s1);
            launchLap(s2);
        } else {              // avg block: MFMA-based rank-1 fold (broadcast avg row)
            LArgs s1 = mkL(LE1, 0, 0, LE2, -1, P1, b1, ACC + (size_t)i * 1024,
                           0, 0, 0, 0, ACC + (size_t)(i - 1) * 1024, 0);
            LArgs s2 = mkL(LE2, LB, LB, LE1, -1, P2, b2, 0,
                           0, 0, 0, 0, ACC + (size_t)i * 1024, 0);
            launchLap(s1);
            launchLap(s2);
        }
    }
}

// Round 13
// 595.859 us; speedup vs baseline: 2.2137x; 1.0443x over previous
//
#include <hip/hip_runtime.h>

#define F 128
#define SPAD 136      // LDS stride (ushorts) for gather S tile
#define NR 16         // rows per tile (16x16 MFMA path)

typedef __attribute__((ext_vector_type(8))) short short8;
typedef __attribute__((ext_vector_type(4))) float f32x4;
typedef unsigned long long ull;

__device__ __forceinline__ float elu_f(float x) {
    return x > 0.f ? x : __expf(x) - 1.f;
}
__device__ __forceinline__ ushort f2bf(float x) {   // fp32 -> bf16 RNE
    unsigned u = __float_as_uint(x);
    u = (u + 0x7FFFu + ((u >> 16) & 1u)) >> 16;
    return (ushort)u;
}
__device__ __forceinline__ float bf2f(ushort u) {
    return __uint_as_float((unsigned)u << 16);
}
__device__ __forceinline__ void bfma8(float* a, float v, short8 u) {
#pragma unroll
    for (int i = 0; i < 8; ++i) a[i] += v * bf2f((ushort)u[i]);
}

// ---------------- fused setup + conv1 ----------------
// blocks 0..87: weight pack (16x16 frag layout); 88..272: rowptr; 273: denom+ACC zero;
// 274..8465: conv1
struct SetupArgs {
    const float* ws0; const float* ws1; const float* ws2; const float* ws3;
    ushort* wd0; ushort* wd1; ushort* wd2; ushort* wd3;
    const int* rows0; const int* rows1; const int* rows2; const int* rows3; const int* rows4;
    int* rp0; int* rp1; int* rp2; int* rp3; int* rp4;
    const float* mask; float* den; float* acc;   // acc: 14*8*128 floats
    const float* in; const float* Wg; const float* bg; const float* Wl; const float* bl;
    ushort* og; ushort* eg; ushort* ol; ushort* el;   // bf16 residual streams
};

__global__ __launch_bounds__(256) void setup_conv1(SetupArgs s) {
    __shared__ ushort tile[16384];
    int b = blockIdx.x, t = threadIdx.x;
    if (b >= 274) {
        int id = (b - 274) * 256 + t;
        int r = id >> 7, c = id & 127;
        float x0 = s.in[r * 3 + 0], x1 = s.in[r * 3 + 1], x2 = s.in[r * 3 + 2];
        float g = x0 * s.Wg[c] + x1 * s.Wg[F + c] + x2 * s.Wg[2 * F + c] + s.bg[c];
        float lo = x0 * s.Wl[c] + x1 * s.Wl[F + c] + x2 * s.Wl[2 * F + c] + s.bl[c];
        s.og[id] = f2bf(g);  s.eg[id] = f2bf(elu_f(g));
        s.ol[id] = f2bf(lo); s.el[id] = f2bf(elu_f(lo));
    } else if (b < 88) {
        const float* src; ushort* dst; int lb;
        if (b < 12)      { src = s.ws0; dst = s.wd0; lb = b; }
        else if (b < 16) { src = s.ws1; dst = s.wd1; lb = b - 12; }
        else if (b < 28) { src = s.ws2; dst = s.wd2; lb = b - 16; }
        else             { src = s.ws3; dst = s.wd3; lb = b - 28; }
        src += (size_t)lb * 16384; dst += (size_t)lb * 16384;
        for (int idx = t; idx < 16384; idx += 256) {
            int k = idx >> 7, nn = idx & 127;
            // 16x16x32 B-frag: lane = lq*16 + col, elem j; k = kt*32 + lq*8 + j
            int kt = k >> 5, lq = (k >> 3) & 3, j = k & 7;
            int wv = nn >> 5, ct = (nn >> 4) & 1, cc = nn & 15;
            tile[((((kt * 4 + wv) * 2 + ct) * 64 + lq * 16 + cc)) * 8 + j] = f2bf(src[idx]);
        }
        __syncthreads();
        ull* td = (ull*)dst; const ull* ts = (const ull*)tile;
        for (int i = t; i < 4096; i += 256) td[i] = ts[i];
    } else if (b < 273) {
        int tid = (b - 88) * 256 + t;
        const int ns[5] = {2048, 4096, 8192, 16384, 16384};
        const int es[5] = {16384, 32768, 65536, 131072, 131072};
        const int* rowsA[5] = {s.rows0, s.rows1, s.rows2, s.rows3, s.rows4};
        int* rpA[5] = {s.rp0, s.rp1, s.rp2, s.rp3, s.rp4};
        int base = 0;
        for (int lv = 0; lv < 5; ++lv) {
            int cnt = ns[lv] + 1;
            if (tid < base + cnt) {
                int r = tid - base;
                const int* rows = rowsA[lv]; int e = es[lv];
                int lo = 0, hi = e;
                while (lo < hi) { int mid = (lo + hi) >> 1; if (rows[mid] < r) lo = mid + 1; else hi = mid; }
                rpA[lv][r] = lo;
                return;
            }
            base += cnt;
        }
    } else {
        __shared__ float red[256];
        float ssum = 0.f;
        for (int i = t; i < 16384; i += 256) ssum += s.mask[i];
        red[t] = ssum; __syncthreads();
        for (int st = 128; st > 0; st >>= 1) { if (t < st) red[t] += red[t + st]; __syncthreads(); }
        if (t == 0) s.den[0] = red[0];
        for (int i = t; i < 14336; i += 256) s.acc[i] = 0.f;
    }
}

// ---------------- unified layer ----------------
struct LArgs {
    const ushort* EA; const ushort* RES; ushort* OUT; ushort* EAOUT;
    const int* rowptr; const int* cols; const float* vals;
    const ushort* Wp; const float* bias;
    const float* accin; const float* den;    // avg mode: 8-replica ACC of prev slot
    const float* mask; float* accout;        // 8-replica out
    ushort* EO; ushort* EE; const ushort* SKIP;
    int epi;  // 0 none, 1 maxpool2, 2 repeat2+skip
    int fin;  // final-head epilogue
    const float* Finp; const ushort* FEB0;
    const float* FgW2; const float* Fgb2; const float* FlW2; const float* Flb2;
    float* Fout;
};

__device__ __forceinline__ void layer_body(const LArgs& a, int blk, ushort* SS, float* FS) {
    const int t = threadIdx.x;
    const int rbase = blk * NR;
    const int w = t >> 6, l = t & 63;
    const int cl = l & 15, lq = l >> 4;       // col-in-tile / K-octet selector
    const bool lap = (a.rowptr != nullptr);
    const bool avg = (a.accin != nullptr);

    if (lap) {
        // 16 lanes per row, 16 concurrent rows/block; lane-parallel cols/vals
        // (one coalesced load covers 16 edges) + full-window issue (1 load/edge/lane).
        const int grp = t >> 4, l16 = t & 15;
        const int lbase = l & ~15;            // group base lane within wave
        const short8* EA8 = (const short8*)a.EA;
        const int row = rbase + grp;
        const int e0 = a.rowptr[row], e1 = a.rowptr[row + 1];
        float acc0[8];
#pragma unroll
        for (int i = 0; i < 8; ++i) acc0[i] = 0.f;
        int myc = 0; float myv = 0.f;
        if (e0 + l16 < e1) { myc = a.cols[e0 + l16]; myv = a.vals[e0 + l16]; }
#pragma unroll 1
        for (int base = e0; base < e1; base += 16) {
            int nc = 0; float nv = 0.f;
            {
                int en = base + 16 + l16;
                if (en < e1) { nc = a.cols[en]; nv = a.vals[en]; }
            }
#pragma unroll
            for (int half = 0; half < 2; ++half) {
                int hb = base + half * 8;
                if (hb < e1) {
                    int cnt = e1 - hb; if (cnt > 8) cnt = 8;
                    int cc[8];
#pragma unroll
                    for (int k = 0; k < 8; ++k) cc[k] = __shfl(myc, lbase + half * 8 + k, 64);
                    short8 ua[8];
#pragma unroll
                    for (int k = 0; k < 8; ++k)
                        if (k < cnt) ua[k] = EA8[(size_t)cc[k] * 16 + l16];
#pragma unroll
                    for (int k = 0; k < 8; ++k)
                        if (k < cnt) {
                            float v = __shfl(myv, lbase + half * 8 + k, 64);
                            bfma8(acc0, v, ua[k]);
                        }
                }
            }
            myc = nc; myv = nv;
        }
        short8 s0;
#pragma unroll
        for (int i = 0; i < 8; ++i) s0[i] = (short)f2bf(acc0[i]);
        *(short8*)(&SS[grp * SPAD + l16 * 8]) = s0;
        __syncthreads();
    } else if (avg) {
        // avg vector (8-replica sum / denom) as a broadcast bf16 A-row in LDS
        if (t < 128) {
            float s = 0.f;
#pragma unroll
            for (int r = 0; r < 8; ++r) s += a.accin[r * 128 + t];
            SS[t] = f2bf(s / a.den[0]);
        }
        __syncthreads();
    }

    // dense-half A-fragments from EA global: row = rbase+cl, k = kt*32 + lq*8 + j
    short8 afrag[4];
    {
        const ushort* ear = a.EA + (size_t)(rbase + cl) * F + lq * 8;
#pragma unroll
        for (int kt = 0; kt < 4; ++kt) afrag[kt] = *(const short8*)(ear + kt * 32);
    }

    f32x4 accA, accB;   // ct = 0, 1 (named: avoid runtime-indexed regs)
#pragma unroll
    for (int i = 0; i < 4; ++i) { accA[i] = 0.f; accB[i] = 0.f; }
#pragma unroll
    for (int kt = 0; kt < 4; ++kt) {
        short8 b0 = *(const short8*)(a.Wp + (size_t)((((kt * 4 + w) * 2 + 0) * 64 + l) * 8));
        short8 b1 = *(const short8*)(a.Wp + (size_t)((((kt * 4 + w) * 2 + 1) * 64 + l) * 8));
        accA = __builtin_amdgcn_mfma_f32_16x16x32_bf16(afrag[kt], b0, accA, 0, 0, 0);
        accB = __builtin_amdgcn_mfma_f32_16x16x32_bf16(afrag[kt], b1, accB, 0, 0, 0);
    }
    if (lap || avg) {
        const ushort* esr = lap ? &SS[cl * SPAD + lq * 8] : &SS[lq * 8];
#pragma unroll
        for (int kt = 0; kt < 4; ++kt) {
            short8 aa = *(const short8*)(esr + kt * 32);
            short8 b0 = *(const short8*)(a.Wp + 16384 + (size_t)((((kt * 4 + w) * 2 + 0) * 64 + l) * 8));
            short8 b1 = *(const short8*)(a.Wp + 16384 + (size_t)((((kt * 4 + w) * 2 + 1) * 64 + l) * 8));
            accA = __builtin_amdgcn_mfma_f32_16x16x32_bf16(aa, b0, accA, 0, 0, 0);
            accB = __builtin_amdgcn_mfma_f32_16x16x32_bf16(aa, b1, accB, 0, 0, 0);
        }
    }

    // C/D: col = cl (+ct*16), row = lq*4 + reg
    const int col0 = w * 32 + cl, col1 = w * 32 + 16 + cl;
    const float bv0 = a.bias[col0], bv1 = a.bias[col1];
    float outv[8];     // [ct*4 + reg]
#pragma unroll
    for (int reg = 0; reg < 4; ++reg) {
        int r = lq * 4 + reg;
        size_t rg = (size_t)(rbase + r);
        float v0 = accA[reg] + bv0;
        float v1 = accB[reg] + bv1;
        if (a.RES) { v0 += bf2f(a.RES[rg * F + col0]); v1 += bf2f(a.RES[rg * F + col1]); }
        outv[reg] = v0; outv[4 + reg] = v1;
        if (a.OUT) { a.OUT[rg * F + col0] = f2bf(v0); a.OUT[rg * F + col1] = f2bf(v1); }
        if (a.EAOUT) { a.EAOUT[rg * F + col0] = f2bf(elu_f(v0)); a.EAOUT[rg * F + col1] = f2bf(elu_f(v1)); }
    }
    if (a.accout) {
        float p0 = 0.f, p1 = 0.f;
#pragma unroll
        for (int reg = 0; reg < 4; ++reg) {
            float mk = a.mask[rbase + lq * 4 + reg];
            p0 += elu_f(outv[reg]) * mk;
            p1 += elu_f(outv[4 + reg]) * mk;
        }
        p0 += __shfl_xor(p0, 16, 64); p0 += __shfl_xor(p0, 32, 64);
        p1 += __shfl_xor(p1, 16, 64); p1 += __shfl_xor(p1, 32, 64);
        if (l < 16) {
            atomicAdd(a.accout + (blk & 7) * 128 + w * 32 + l, p0);
            atomicAdd(a.accout + (blk & 7) * 128 + w * 32 + 16 + l, p1);
        }
    }
    if (a.epi == 1) {          // fused maxpool2 (pairs lane-local: rows lq*4+{0..3})
        int rb2 = rbase >> 1;
#pragma unroll
        for (int ct = 0; ct < 2; ++ct)
#pragma unroll
            for (int e2 = 0; e2 < 2; ++e2) {
                float pv = fmaxf(outv[ct * 4 + e2 * 2], outv[ct * 4 + e2 * 2 + 1]);
                size_t idx = (size_t)(rb2 + lq * 2 + e2) * F + (ct ? col1 : col0);
                a.EO[idx] = f2bf(pv);
                a.EE[idx] = f2bf(elu_f(pv));
            }
    } else if (a.epi == 2) {   // fused repeat2 + skip add
#pragma unroll
        for (int ct = 0; ct < 2; ++ct)
#pragma unroll
            for (int reg = 0; reg < 4; ++reg) {
                int r = lq * 4 + reg;
                size_t R0 = (size_t)(2 * (rbase + r)) * F + (ct ? col1 : col0);
                float v0 = outv[ct * 4 + reg] + bf2f(a.SKIP[R0]);
                float v1 = outv[ct * 4 + reg] + bf2f(a.SKIP[R0 + F]);
                a.EO[R0] = f2bf(v0);     a.EO[R0 + F] = f2bf(v1);
                a.EE[R0] = f2bf(elu_f(v0)); a.EE[R0 + F] = f2bf(elu_f(v1));
            }
    }
    if (a.fin) {               // fused final head (16 rows/block)
        __syncthreads();
        if (t < 32) FS[t] = 0.f;
        __syncthreads();
#pragma unroll
        for (int ct = 0; ct < 2; ++ct) {
            float lw = a.FlW2[ct ? col1 : col0];
#pragma unroll
            for (int reg = 0; reg < 4; ++reg)
                atomicAdd(&FS[lq * 4 + reg], elu_f(outv[ct * 4 + reg]) * lw);
        }
        for (int idx = t; idx < 16 * 128; idx += 256) {
            int r = idx >> 7, cc = idx & 127;
            atomicAdd(&FS[16 + r], bf2f(a.FEB0[(size_t)(rbase + r) * F + cc]) * a.FgW2[2 * cc]);
        }
        __syncthreads();
        if (t < 16) {
            int rg = rbase + t;
            float base = a.Finp[rg * 3 + 0];
            float sg = FS[16 + t] + a.Fgb2[0] + base;
            float sl = FS[t] + a.Flb2[0] + base;
            float wg = 1.f / (1.f + __expf(-sg));
            a.Fout[rg] = sg;
            a.Fout[16384 + rg] = sl;
            a.Fout[32768 + rg] = wg * sg + (1.f - wg) * sl;
        }
    }
}

__global__ __launch_bounds__(256)
void dual_layer(LArgs A, LArgs B, int nA) {
    __shared__ ushort SS[NR * SPAD];
    __shared__ float FS[64];
    bool isA = (int)blockIdx.x < nA;
    const LArgs& a = isA ? A : B;
    int blk = isA ? blockIdx.x : blockIdx.x - nA;
    layer_body(a, blk, SS, FS);
}

extern "C" void kernel_launch(void* const* d_in, const int* in_sizes, int n_in,
                              void* d_out, int out_size, void* d_ws, size_t ws_size,
                              hipStream_t stream) {
    (void)in_sizes; (void)n_in; (void)out_size; (void)ws_size;
    const float* inputs = (const float*)d_in[0];
    const float* mask1  = (const float*)d_in[2];
    const int*   lrows[5] = {(const int*)d_in[3], (const int*)d_in[6], (const int*)d_in[9],
                             (const int*)d_in[12], (const int*)d_in[15]};
    const int*   lcols[5] = {(const int*)d_in[4], (const int*)d_in[7], (const int*)d_in[10],
                             (const int*)d_in[13], (const int*)d_in[16]};
    const float* lvals[5] = {(const float*)d_in[5], (const float*)d_in[8], (const float*)d_in[11],
                             (const float*)d_in[14], (const float*)d_in[17]};
    const float* gW1 = (const float*)d_in[18];
    const float* gb1 = (const float*)d_in[19];
    const float* gdW = (const float*)d_in[20];
    const float* gdb = (const float*)d_in[21];
    const float* glW = (const float*)d_in[22];
    const float* glb = (const float*)d_in[23];
    const float* guW = (const float*)d_in[24];
    const float* gub = (const float*)d_in[25];
    const float* gW2 = (const float*)d_in[26];
    const float* gb2 = (const float*)d_in[27];
    const float* lW1 = (const float*)d_in[28];
    const float* lb1 = (const float*)d_in[29];
    const float* lrW = (const float*)d_in[30];
    const float* lrb = (const float*)d_in[31];
    const float* lW2 = (const float*)d_in[32];
    const float* lb2 = (const float*)d_in[33];
    float* out = (float*)d_out;

    const int N = 16384;
    const int nlev[5] = {2048, 4096, 8192, 16384, 16384};

    char* ws = (char*)d_ws;
    size_t off = 0;
    auto alloc = [&](size_t bytes) -> char* {
        char* p = ws + off;
        off = (off + bytes + 255) & ~(size_t)255;
        return p;
    };
    // bf16 residual / skip / pool streams
    ushort* BUF0 = (ushort*)alloc((size_t)N * F * 2);
    ushort* GU2  = (ushort*)alloc((size_t)N * F * 2);
    ushort* G2   = (ushort*)alloc((size_t)N * F * 2);
    ushort* D8   = (ushort*)alloc((size_t)8192 * F * 2);
    ushort* D4   = (ushort*)alloc((size_t)4096 * F * 2);
    ushort* D2   = (ushort*)alloc((size_t)2048 * F * 2);
    ushort* LB   = (ushort*)alloc((size_t)N * F * 2);
    ushort* EB0 = (ushort*)alloc((size_t)N * F * 2);
    ushort* EG1 = (ushort*)alloc((size_t)N * F * 2);
    ushort* EG2 = (ushort*)alloc((size_t)N * F * 2);
    ushort* ED8 = (ushort*)alloc((size_t)8192 * F * 2);
    ushort* ED4 = (ushort*)alloc((size_t)4096 * F * 2);
    ushort* ED2 = (ushort*)alloc((size_t)2048 * F * 2);
    ushort* LE1 = (ushort*)alloc((size_t)N * F * 2);
    ushort* LE2 = (ushort*)alloc((size_t)N * F * 2);
    int* rp[5];
    for (int i = 0; i < 5; ++i) rp[i] = (int*)alloc((size_t)(nlev[i] + 1) * 4);
    float* ACC = (float*)alloc((size_t)14 * 8 * 128 * 4);   // 8 replicas per slot
    float* DEN = (float*)alloc(4);
    ushort* Pd = (ushort*)alloc((size_t)12 * 16384 * 2);
    ushort* Pl = (ushort*)alloc((size_t)4  * 16384 * 2);
    ushort* Pu = (ushort*)alloc((size_t)12 * 16384 * 2);
    ushort* Pr = (ushort*)alloc((size_t)60 * 16384 * 2);

    SetupArgs sa;
    sa.ws0 = gdW; sa.ws1 = glW; sa.ws2 = guW; sa.ws3 = lrW;
    sa.wd0 = Pd;  sa.wd1 = Pl;  sa.wd2 = Pu;  sa.wd3 = Pr;
    sa.rows0 = lrows[0]; sa.rows1 = lrows[1]; sa.rows2 = lrows[2];
    sa.rows3 = lrows[3]; sa.rows4 = lrows[4];
    sa.rp0 = rp[0]; sa.rp1 = rp[1]; sa.rp2 = rp[2]; sa.rp3 = rp[3]; sa.rp4 = rp[4];
    sa.mask = mask1; sa.den = DEN; sa.acc = ACC;
    sa.in = inputs; sa.Wg = gW1; sa.bg = gb1; sa.Wl = lW1; sa.bl = lb1;
    sa.og = BUF0; sa.eg = EB0; sa.ol = LB; sa.el = LE1;
    setup_conv1<<<274 + 8192, 256, 0, stream>>>(sa);

    const size_t PSZ = 2 * 16384;   // packed bf16 stride per sub-layer (2 halves)

    auto mkL = [&](const ushort* ea, const ushort* res, ushort* o, ushort* eao,
                   int lv, const ushort* wp, const float* bias, float* accout,
                   int epi, ushort* eo, ushort* ee, const ushort* skip,
                   const float* accin, int fin) {
        LArgs x;
        x.EA = ea; x.RES = res; x.OUT = o; x.EAOUT = eao;
        x.rowptr = (lv >= 0) ? rp[lv] : nullptr;
        x.cols = (lv >= 0) ? lcols[lv] : nullptr;
        x.vals = (lv >= 0) ? lvals[lv] : nullptr;
        x.Wp = wp; x.bias = bias;
        x.accin = accin; x.den = DEN;
        x.mask = mask1; x.accout = accout;
        x.EO = eo; x.EE = ee; x.SKIP = skip; x.epi = epi;
        x.fin = fin;
        x.Finp = inputs; x.FEB0 = EB0;
        x.FgW2 = gW2; x.Fgb2 = gb2; x.FlW2 = lW2; x.Flb2 = lb2; x.Fout = out;
        return x;
    };

    // ---- global branch slots (pool/upadd fused into sub2 epilogues) ----
    LArgs gs[14]; int gn[14];
    gs[0]  = mkL(EB0, 0, 0, EG1, 3, Pd + 0 * PSZ, gdb + 0,   0, 0, 0, 0, 0, 0, 0);  gn[0]  = 16384;
    gs[1]  = mkL(EG1, BUF0, 0, 0, 3, Pd + 1 * PSZ, gdb + 128, 0, 1, D8, ED8, 0, 0, 0); gn[1] = 16384;
    gs[2]  = mkL(ED8, 0, 0, EG1, 2, Pd + 2 * PSZ, gdb + 256, 0, 0, 0, 0, 0, 0, 0);  gn[2]  = 8192;
    gs[3]  = mkL(EG1, D8, 0, 0, 2, Pd + 3 * PSZ, gdb + 384, 0, 1, D4, ED4, 0, 0, 0); gn[3]  = 8192;
    gs[4]  = mkL(ED4, 0, 0, EG1, 1, Pd + 4 * PSZ, gdb + 512, 0, 0, 0, 0, 0, 0, 0);  gn[4]  = 4096;
    gs[5]  = mkL(EG1, D4, 0, 0, 1, Pd + 5 * PSZ, gdb + 640, 0, 1, D2, ED2, 0, 0, 0); gn[5]  = 4096;
    gs[6]  = mkL(ED2, 0, 0, EG1, 0, Pl + 0 * PSZ, glb + 0,   0, 0, 0, 0, 0, 0, 0);  gn[6]  = 2048;
    gs[7]  = mkL(EG1, D2, 0, 0, 0, Pl + 1 * PSZ, glb + 128, 0, 2, GU2, EG2, D4, 0, 0); gn[7] = 2048;
    gs[8]  = mkL(EG2, 0, 0, EG1, 1, Pu + 0 * PSZ, gub + 0,   0, 0, 0, 0, 0, 0, 0);  gn[8]  = 4096;
    gs[9]  = mkL(EG1, GU2, 0, 0, 1, Pu + 1 * PSZ, gub + 128, 0, 2, G2, EG2, D8, 0, 0); gn[9] = 4096;
    gs[10] = mkL(EG2, 0, 0, EG1, 2, Pu + 2 * PSZ, gub + 256, 0, 0, 0, 0, 0, 0, 0);  gn[10] = 8192;
    gs[11] = mkL(EG1, G2, 0, 0, 2, Pu + 3 * PSZ, gub + 384, 0, 2, GU2, EG2, BUF0, 0, 0); gn[11] = 8192;
    gs[12] = mkL(EG2, 0, 0, EG1, 3, Pu + 4 * PSZ, gub + 512, 0, 0, 0, 0, 0, 0, 0);  gn[12] = 16384;
    gs[13] = mkL(EG1, GU2, 0, EB0, 3, Pu + 5 * PSZ, gub + 640, 0, 0, 0, 0, 0, 0, 0); gn[13] = 16384;

    const int NB_LOC = N / NR;   // 1024 local blocks
    int gi = 0;
    auto launchLap = [&](const LArgs& loc) {
        if (gi < 14) {
            int na = gn[gi] / NR;
            dual_layer<<<na + NB_LOC, 256, 0, stream>>>(gs[gi], loc, na);
            ++gi;
        } else {
            dual_layer<<<NB_LOC, 256, 0, stream>>>(loc, loc, NB_LOC);
        }
    };

    for (int i = 0; i < 15; ++i) {
        const ushort* P1 = Pr + (size_t)(2 * i) * PSZ;
        const ushort* P2 = Pr + (size_t)(2 * i + 1) * PSZ;
        const float* b1 = lrb + (size_t)i * 256;
        const float* b2 = b1 + 128;
        if ((i & 1) == 0) {   // lap block on L (level 4)
            LArgs s1 = mkL(LE1, 0, 0, LE2, 4, P1, b1, 0, 0, 0, 0, 0, 0, 0);
            float* accout = (i <= 12) ? (ACC + (size_t)i * 1024) : nullptr;
            int fin = (i == 14);
            LArgs s2 = mkL(LE2, LB, fin ? nullptr : LB, fin ? nullptr : LE1, 4,
                           P2, b2, accout, 0, 0, 0, 0, 0, fin);
            launchLap(s1);
            launchLap(s2);
        } else {              // avg block: MFMA-based rank-1 fold (broadcast avg row)
            LArgs s1 = mkL(LE1, 0, 0, LE2, -1, P1, b1, ACC + (size_t)i * 1024,
                           0, 0, 0, 0, ACC + (size_t)(i - 1) * 1024, 0);
            LArgs s2 = mkL(LE2, LB, LB, LE1, -1, P2, b2, 0,
                           0, 0, 0, 0, ACC + (size_t)i * 1024, 0);
            launchLap(s1);
            launchLap(s2);
        }
    }
}